// Round 11
// baseline (403.406 us; speedup 1.0000x reference)
//
#include <hip/hip_runtime.h>
#include <hip/hip_bf16.h>

#define BB 2
#define SS 2048
#define DD 1024
#define HH 16
#define DKV 64

typedef __attribute__((ext_vector_type(8))) short short8;
typedef __attribute__((ext_vector_type(4))) short short4_t;
typedef __attribute__((ext_vector_type(4))) float f32x4;

#define MFMA16(a, b, c) __builtin_amdgcn_mfma_f32_16x16x32_bf16(a, b, c, 0, 0, 0)

__device__ __forceinline__ short f2bf(float f) {
    __hip_bfloat16 h = __float2bfloat16(f);
    union { __hip_bfloat16 h; short s; } u;
    u.h = h;
    return u.s;
}

// ===========================================================================
// Phase bodies (each called under a block-uniform branch)
// ===========================================================================

__device__ __forceinline__ void body_maskpack(
    const int* __restrict__ mask, unsigned long long* __restrict__ bits,
    int batch, int bid128)
{
    const int t = threadIdx.x, lane = t & 63, wave = t >> 6;
    const int base = batch * 65536 + bid128 * 512 + wave * 128;
    #pragma unroll 4
    for (int wi = base; wi < base + 128; ++wi) {
        const int mv = mask[(size_t)wi * 64 + lane];
        const unsigned long long bal = __ballot(mv != 0);
        if (lane == 0) bits[wi] = bal;
    }
}

// proj GEMM: A[4096x1024]bf16 @ WT[n][k]bf16 + bias.
// zmode 0/1 -> head layout [b][h][s][64]; zmode 2 -> vT[b][h][d][s].
__device__ __forceinline__ void body_projgemm(
    const short* __restrict__ A, const short* __restrict__ WT,
    const float* __restrict__ bias, short* __restrict__ outp,
    int zmode, int batch, int bx, int by, short* lds)
{
    short (*As)[40] = (short(*)[40])lds;
    short (*Bs)[40] = (short(*)[40])(lds + 5120);
    const int t = threadIdx.x, lane = t & 63, wave = t >> 6;
    const int wm = wave >> 1, wn = wave & 1;
    const int m0 = batch * SS + bx * 128, n0 = by * 128;
    const int lr = lane & 15, kb = (lane >> 4) * 8;
    const int row2 = t >> 1, kk2 = (t & 1) * 16;

    f32x4 acc[4][4] = {};
    for (int k0 = 0; k0 < DD; k0 += 32) {
        __syncthreads();
        {
            const short8* srca = (const short8*)(A + (size_t)(m0 + row2) * DD + k0 + kk2);
            *(short8*)&As[row2][kk2]     = srca[0];
            *(short8*)&As[row2][kk2 + 8] = srca[1];
            const short8* srcw = (const short8*)(WT + (size_t)(n0 + row2) * DD + k0 + kk2);
            *(short8*)&Bs[row2][kk2]     = srcw[0];
            *(short8*)&Bs[row2][kk2 + 8] = srcw[1];
        }
        __syncthreads();
        short8 af[4], bfr[4];
        #pragma unroll
        for (int i = 0; i < 4; i++) af[i]  = *(const short8*)&As[wm * 64 + i * 16 + lr][kb];
        #pragma unroll
        for (int j = 0; j < 4; j++) bfr[j] = *(const short8*)&Bs[wn * 64 + j * 16 + lr][kb];
        #pragma unroll
        for (int i = 0; i < 4; i++)
            #pragma unroll
            for (int j = 0; j < 4; j++)
                acc[i][j] = MFMA16(af[i], bfr[j], acc[i][j]);
    }

    if (zmode != 2) {
        #pragma unroll
        for (int j = 0; j < 4; j++) {
            const int col = n0 + wn * 64 + j * 16 + lr;
            const float bvv = bias[col];
            const int h = col >> 6, d = col & 63;
            #pragma unroll
            for (int i = 0; i < 4; i++) {
                #pragma unroll
                for (int r = 0; r < 4; r++) {
                    const int m = m0 + wm * 64 + i * 16 + (lane >> 4) * 4 + r;
                    const int b = m >> 11, s = m & (SS - 1);
                    outp[(((size_t)(b * HH + h)) * SS + s) * DKV + d] =
                        f2bf(acc[i][j][r] + bvv);
                }
            }
        }
    } else {
        #pragma unroll
        for (int j = 0; j < 4; j++) {
            const int col = n0 + wn * 64 + j * 16 + lr;
            const float bvv = bias[col];
            const int h = col >> 6, d = col & 63;
            #pragma unroll
            for (int i = 0; i < 4; i++) {
                const int m = m0 + wm * 64 + i * 16 + (lane >> 4) * 4;
                const int b = m >> 11, s = m & (SS - 1);
                short4_t pk;
                #pragma unroll
                for (int r = 0; r < 4; r++) pk[r] = f2bf(acc[i][j][r] + bvv);
                *(short4_t*)(outp + ((size_t)(b * HH + h) * DKV + d) * SS + s) = pk;
            }
        }
    }
}

// attention compute: 256 thr / 4 waves, 64 q-rows per block.
__device__ __forceinline__ void body_attn(
    const short* __restrict__ qh, const short* __restrict__ kh,
    const short* __restrict__ vT, const unsigned long long* __restrict__ bits,
    float* __restrict__ linvb, short* __restrict__ ctx,
    int batch, int logical, short* lds)
{
    short (*Ks)[64][72] = (short(*)[64][72])lds;          // 2x9216
    short (*Vs)[64][72] = (short(*)[64][72])(lds + 9216);
    short (*Ps)[16][72] = (short(*)[16][72])(lds + 18432); // 4x1152
    const int t = threadIdx.x, lane = t & 63, w = t >> 6;
    const int qt = logical & 31;
    const int h  = logical >> 5;
    const int bh = batch * HH + h;
    const int q0w = qt * 64 + w * 16;
    const size_t headbase = (size_t)bh * SS * DKV;
    const int lr = lane & 15, kb = (lane >> 4) * 8;
    const int rbase = (lane >> 4) * 4;

    const short* kbase = kh + headbase;
    const short* vbase = vT + (size_t)bh * DKV * SS;
    const unsigned long long* bitrow = bits + ((size_t)batch * SS + q0w) * (SS / 64);

    const int srow = t >> 2, sc8 = (t & 3) * 16;
    const short* kstg = kbase + (size_t)srow * DKV + sc8;
    const short* vstg = vbase + (size_t)srow * SS + sc8;

    const short* qrp = qh + headbase + (size_t)(q0w + lr) * DKV;
    const short8 aq0 = *(const short8*)(qrp + kb);
    const short8 aq1 = *(const short8*)(qrp + 32 + kb);

    float lsum[4] = {0.f, 0.f, 0.f, 0.f};
    f32x4 cacc[4] = {};

    short8 ka = *(const short8*)(kstg);
    short8 kc = *(const short8*)(kstg + 8);
    short8 va = *(const short8*)(vstg);
    short8 vc = *(const short8*)(vstg + 8);
    *(short8*)&Ks[0][srow][sc8]     = ka;
    *(short8*)&Ks[0][srow][sc8 + 8] = kc;
    *(short8*)&Vs[0][srow][sc8]     = va;
    *(short8*)&Vs[0][srow][sc8 + 8] = vc;
    __syncthreads();
    for (int kt = 0; kt < 32; ++kt) {
        const int cur = kt & 1;
        if (kt + 1 < 32) {
            const short* kn = kstg + (size_t)(kt + 1) * 64 * DKV;
            const short* vn = vstg + (size_t)(kt + 1) * 64;
            ka = *(const short8*)(kn);
            kc = *(const short8*)(kn + 8);
            va = *(const short8*)(vn);
            vc = *(const short8*)(vn + 8);
        }
        f32x4 sc[4];
        __builtin_amdgcn_s_setprio(1);
        #pragma unroll
        for (int fc = 0; fc < 4; ++fc) {
            short8 bk0 = *(const short8*)&Ks[cur][fc * 16 + lr][kb];
            short8 bk1 = *(const short8*)&Ks[cur][fc * 16 + lr][32 + kb];
            f32x4 s = {0.f, 0.f, 0.f, 0.f};
            s = MFMA16(aq0, bk0, s);
            s = MFMA16(aq1, bk1, s);
            sc[fc] = s;
        }
        __builtin_amdgcn_s_setprio(0);
        unsigned long long mw[4];
        #pragma unroll
        for (int r = 0; r < 4; ++r)
            mw[r] = bitrow[(size_t)(rbase + r) * (SS / 64) + kt];
        #pragma unroll
        for (int fc = 0; fc < 4; ++fc)
            #pragma unroll
            for (int r = 0; r < 4; ++r) {
                const bool masked = (mw[r] >> (fc * 16 + lr)) & 1ull;
                const float p = masked ? 0.f : __expf(sc[fc][r] * 0.125f);
                lsum[r] += p;
                Ps[w][rbase + r][fc * 16 + lr] = f2bf(p);
            }
        short8 ap0 = *(const short8*)&Ps[w][lr][kb];
        short8 ap1 = *(const short8*)&Ps[w][lr][32 + kb];
        __builtin_amdgcn_s_setprio(1);
        #pragma unroll
        for (int fd = 0; fd < 4; ++fd) {
            short8 bv0 = *(const short8*)&Vs[cur][fd * 16 + lr][kb];
            short8 bv1 = *(const short8*)&Vs[cur][fd * 16 + lr][32 + kb];
            cacc[fd] = MFMA16(ap0, bv0, cacc[fd]);
            cacc[fd] = MFMA16(ap1, bv1, cacc[fd]);
        }
        __builtin_amdgcn_s_setprio(0);
        if (kt + 1 < 32) {
            *(short8*)&Ks[cur ^ 1][srow][sc8]     = ka;
            *(short8*)&Ks[cur ^ 1][srow][sc8 + 8] = kc;
            *(short8*)&Vs[cur ^ 1][srow][sc8]     = va;
            *(short8*)&Vs[cur ^ 1][srow][sc8 + 8] = vc;
        }
        __syncthreads();
    }
    #pragma unroll
    for (int r = 0; r < 4; r++) {
        float s = lsum[r];
        s += __shfl_xor(s, 1);
        s += __shfl_xor(s, 2);
        s += __shfl_xor(s, 4);
        s += __shfl_xor(s, 8);
        lsum[r] = s;
    }
    float linv[4];
    #pragma unroll
    for (int r = 0; r < 4; r++) linv[r] = 1.f / lsum[r];

    if (lr == 0) {
        #pragma unroll
        for (int r = 0; r < 4; r++)
            linvb[(size_t)bh * SS + q0w + rbase + r] = linv[r];
    }
    #pragma unroll
    for (int fd = 0; fd < 4; ++fd)
        #pragma unroll
        for (int r = 0; r < 4; r++) {
            const int qrow = q0w + rbase + r;
            ctx[((size_t)batch * SS + qrow) * DD + h * DKV + fd * 16 + lr] =
                f2bf(cacc[fd][r] * linv[r]);
        }
}

// output GEMM: out = ctx(bf16) @ WT + bias + resid (fp32 out)
__device__ __forceinline__ void body_outproj(
    const short* __restrict__ Actx, const short* __restrict__ WT,
    const float* __restrict__ bias, const float* __restrict__ resid,
    float* __restrict__ out, int batch, int bx, int by, short* lds)
{
    short (*As)[40] = (short(*)[40])lds;
    short (*Bs)[40] = (short(*)[40])(lds + 5120);
    const int t = threadIdx.x, lane = t & 63, wave = t >> 6;
    const int wm = wave >> 1, wn = wave & 1;
    const int m0 = batch * SS + bx * 128, n0 = by * 128;
    const int lr = lane & 15, kb = (lane >> 4) * 8;
    const int row2 = t >> 1, kk2 = (t & 1) * 16;

    f32x4 acc[4][4] = {};
    for (int k0 = 0; k0 < DD; k0 += 32) {
        __syncthreads();
        {
            const short8* srca = (const short8*)(Actx + (size_t)(m0 + row2) * DD + k0 + kk2);
            *(short8*)&As[row2][kk2]     = srca[0];
            *(short8*)&As[row2][kk2 + 8] = srca[1];
            const short8* srcw = (const short8*)(WT + (size_t)(n0 + row2) * DD + k0 + kk2);
            *(short8*)&Bs[row2][kk2]     = srcw[0];
            *(short8*)&Bs[row2][kk2 + 8] = srcw[1];
        }
        __syncthreads();
        short8 af[4], bfr[4];
        #pragma unroll
        for (int i = 0; i < 4; i++) af[i]  = *(const short8*)&As[wm * 64 + i * 16 + lr][kb];
        #pragma unroll
        for (int j = 0; j < 4; j++) bfr[j] = *(const short8*)&Bs[wn * 64 + j * 16 + lr][kb];
        #pragma unroll
        for (int i = 0; i < 4; i++)
            #pragma unroll
            for (int j = 0; j < 4; j++)
                acc[i][j] = MFMA16(af[i], bfr[j], acc[i][j]);
    }
    #pragma unroll
    for (int j = 0; j < 4; j++) {
        const int col = n0 + wn * 64 + j * 16 + lr;
        const float bvv = bias[col];
        #pragma unroll
        for (int i = 0; i < 4; i++) {
            #pragma unroll
            for (int r = 0; r < 4; r++) {
                const int m = m0 + wm * 64 + i * 16 + (lane >> 4) * 4 + r;
                out[(size_t)m * DD + col] = acc[i][j][r] + bvv + resid[(size_t)m * DD + col];
            }
        }
    }
}

// attn store slice: 64q x 512k tile, recompute scores, stream fp32 attn.
__device__ __forceinline__ void body_store(
    const short* __restrict__ qh, const short* __restrict__ kh,
    const unsigned long long* __restrict__ bits, const float* __restrict__ linvb,
    float* __restrict__ attn, int batch, int sb, short* lds)
{
    short (*Ks)[72] = (short(*)[72])lds;   // 512 x 72
    const int t = threadIdx.x, lane = t & 63, w = t >> 6;
    const int qt = sb & 31;
    const int kc = (sb >> 5) & 3;
    const int hh = sb >> 7;                // 0..15
    const int bh = batch * HH + hh;
    const int q0w = qt * 64 + w * 16;
    const int k0c = kc * 512;
    const size_t headbase = (size_t)bh * SS * DKV;
    const int lr = lane & 15, kb = (lane >> 4) * 8;
    const int rbase = (lane >> 4) * 4;

    {
        const short* kb2 = kh + headbase + (size_t)k0c * DKV;
        const int c8 = (t & 7) * 8;
        #pragma unroll
        for (int sweep = 0; sweep < 16; ++sweep) {
            const int row = (t >> 3) + sweep * 32;
            *(short8*)&Ks[row][c8] = *(const short8*)(kb2 + (size_t)row * DKV + c8);
        }
    }

    const short* qrp = qh + headbase + (size_t)(q0w + lr) * DKV;
    const short8 aq0 = *(const short8*)(qrp + kb);
    const short8 aq1 = *(const short8*)(qrp + 32 + kb);

    float linv[4];
    #pragma unroll
    for (int r = 0; r < 4; ++r)
        linv[r] = linvb[(size_t)bh * SS + q0w + rbase + r];

    const unsigned long long* bitrow = bits + ((size_t)batch * SS + q0w) * (SS / 64);
    float* arow = attn + ((size_t)bh * SS + q0w) * SS + k0c;

    __syncthreads();

    for (int g = 0; g < 8; ++g) {
        unsigned long long mw[4];
        #pragma unroll
        for (int r = 0; r < 4; ++r)
            mw[r] = bitrow[(size_t)(rbase + r) * (SS / 64) + kc * 8 + g];
        #pragma unroll
        for (int fc = 0; fc < 4; ++fc) {
            const int col = g * 64 + fc * 16;
            short8 bk0 = *(const short8*)&Ks[col + lr][kb];
            short8 bk1 = *(const short8*)&Ks[col + lr][32 + kb];
            f32x4 s = {0.f, 0.f, 0.f, 0.f};
            s = MFMA16(aq0, bk0, s);
            s = MFMA16(aq1, bk1, s);
            #pragma unroll
            for (int r = 0; r < 4; ++r) {
                const bool masked = (mw[r] >> (fc * 16 + lr)) & 1ull;
                const float p = masked ? 0.f : __expf(s[r] * 0.125f) * linv[r];
                arow[(size_t)(rbase + r) * SS + col + lr] = p;
            }
        }
    }
}

__device__ __forceinline__ void body_ln(
    float* __restrict__ io, const float* __restrict__ g, const float* __restrict__ bta,
    int row, float* sh)
{
    const int t = threadIdx.x;
    float* p = io + (size_t)row * DD;
    float4 x = *(float4*)(p + t * 4);
    float s  = x.x + x.y + x.z + x.w;
    float s2 = x.x * x.x + x.y * x.y + x.z * x.z + x.w * x.w;
    #pragma unroll
    for (int off = 32; off; off >>= 1) {
        s  += __shfl_xor(s, off);
        s2 += __shfl_xor(s2, off);
    }
    const int w = t >> 6, l = t & 63;
    if (!l) { sh[w] = s; sh[4 + w] = s2; }
    __syncthreads();
    s  = sh[0] + sh[1] + sh[2] + sh[3];
    s2 = sh[4] + sh[5] + sh[6] + sh[7];
    const float mu  = s * (1.f / DD);
    const float var = s2 * (1.f / DD) - mu * mu;
    const float rs  = rsqrtf(var + 1e-5f);
    float4 gv = *(const float4*)(g + t * 4);
    float4 bv = *(const float4*)(bta + t * 4);
    float4 o;
    o.x = (x.x - mu) * rs * gv.x + bv.x;
    o.y = (x.y - mu) * rs * gv.y + bv.y;
    o.z = (x.z - mu) * rs * gv.z + bv.z;
    o.w = (x.w - mu) * rs * gv.w + bv.w;
    *(float4*)(p + t * 4) = o;
}

// ===========================================================================
// Kernels
// ===========================================================================

// z=0..3: W -> WT bf16; z=4..6: q/k/v fp32 -> bf16
__global__ __launch_bounds__(256) void wtrans_kernel(
    const float* __restrict__ w0, const float* __restrict__ w1,
    const float* __restrict__ w2, const float* __restrict__ w3,
    const float* __restrict__ qf, const float* __restrict__ kf, const float* __restrict__ vf,
    short* __restrict__ o0, short* __restrict__ o1,
    short* __restrict__ o2, short* __restrict__ o3,
    short* __restrict__ oq, short* __restrict__ ok, short* __restrict__ ov)
{
    const int z = blockIdx.z;
    const int t = threadIdx.x;
    if (z >= 4) {
        const float* src = (z == 4) ? qf : (z == 5) ? kf : vf;
        short* dst = (z == 4) ? oq : (z == 5) ? ok : ov;
        size_t idx = ((size_t)(blockIdx.y * 16 + blockIdx.x) * 256 + t) * 8;
        #pragma unroll
        for (int it = 0; it < 8; ++it, idx += 524288) {
            float4 a = *(const float4*)(src + idx);
            float4 b = *(const float4*)(src + idx + 4);
            short8 p = { f2bf(a.x), f2bf(a.y), f2bf(a.z), f2bf(a.w),
                         f2bf(b.x), f2bf(b.y), f2bf(b.z), f2bf(b.w) };
            *(short8*)(dst + idx) = p;
        }
        return;
    }
    const float* W = (z == 0) ? w0 : (z == 1) ? w1 : (z == 2) ? w2 : w3;
    short* O = (z == 0) ? o0 : (z == 1) ? o1 : (z == 2) ? o2 : o3;
    __shared__ short T[64][72];
    const int k0 = blockIdx.x * 64, n0 = blockIdx.y * 64;
    const int row = t >> 2, c = (t & 3) * 16;
    const float* src = W + (size_t)(k0 + row) * DD + n0 + c;
    #pragma unroll
    for (int i = 0; i < 16; i += 4) {
        float4 f = *(const float4*)(src + i);
        T[c + i + 0][row] = f2bf(f.x);
        T[c + i + 1][row] = f2bf(f.y);
        T[c + i + 2][row] = f2bf(f.z);
        T[c + i + 3][row] = f2bf(f.w);
    }
    __syncthreads();
    const int nr = t >> 2, kc = (t & 3) * 16;
    *(short8*)(O + (size_t)(n0 + nr) * DD + k0 + kc)     = *(const short8*)&T[nr][kc];
    *(short8*)(O + (size_t)(n0 + nr) * DD + k0 + kc + 8) = *(const short8*)&T[nr][kc + 8];
}

// batch-sliced projections: grid (16,8,4); z=0 mask pack, z=1..3 q/k/v
__global__ __launch_bounds__(256) void proj3b_kernel(
    const short* __restrict__ A0, const short* __restrict__ A1, const short* __restrict__ A2,
    const short* __restrict__ WT0, const short* __restrict__ WT1, const short* __restrict__ WT2,
    const float* __restrict__ bq, const float* __restrict__ bk, const float* __restrict__ bv,
    short* __restrict__ o0, short* __restrict__ o1, short* __restrict__ o2,
    const int* __restrict__ mask, unsigned long long* __restrict__ bits, int batch)
{
    __shared__ __align__(16) short UB[10240];
    if (blockIdx.z == 0) {
        body_maskpack(mask, bits, batch, blockIdx.y * 16 + blockIdx.x);
        return;
    }
    const int z = blockIdx.z - 1;
    const short* A  = (z == 0) ? A0 : (z == 1) ? A1 : A2;
    const short* WT = (z == 0) ? WT0 : (z == 1) ? WT1 : WT2;
    const float* bias = (z == 0) ? bq : (z == 1) ? bk : bv;
    short* outp = (z == 0) ? o0 : (z == 1) ? o1 : o2;
    body_projgemm(A, WT, bias, outp, z, batch, blockIdx.x, blockIdx.y, UB);
}

// uber0: attn(b0) [0,512) + proj3(b1) [512,896) + maskpack(b1) [896,1024)
__global__ __launch_bounds__(256) void uber0_kernel(
    const short* __restrict__ qb, const short* __restrict__ kbf, const short* __restrict__ vbf,
    const short* __restrict__ WT0, const short* __restrict__ WT1, const short* __restrict__ WT2,
    const float* __restrict__ bq, const float* __restrict__ bk, const float* __restrict__ bv,
    short* __restrict__ qh, short* __restrict__ kh, short* __restrict__ vT,
    const int* __restrict__ mask, unsigned long long* __restrict__ bits,
    float* __restrict__ linvb, short* __restrict__ ctx)
{
    __shared__ __align__(16) short UB[23040];
    const int bid = blockIdx.x;
    if (bid < 512) {
        const int logical = (bid & 7) * 64 + (bid >> 3);
        body_attn(qh, kh, vT, bits, linvb, ctx, 0, logical, UB);
        return;
    }
    const int rem = bid - 512;
    if (rem < 384) {
        const int z = rem >> 7;
        const int local = rem & 127;
        const short* A  = (z == 0) ? qb : (z == 1) ? kbf : vbf;
        const short* WT = (z == 0) ? WT0 : (z == 1) ? WT1 : WT2;
        const float* bias = (z == 0) ? bq : (z == 1) ? bk : bv;
        short* outp = (z == 0) ? qh : (z == 1) ? kh : vT;
        body_projgemm(A, WT, bias, outp, z, 1, local & 15, local >> 4, UB);
        return;
    }
    body_maskpack(mask, bits, 1, rem - 384);
}

// uber1: attn(b1) [0,512) + outproj(b0) [512,640) + store(b0) [640,2688)
__global__ __launch_bounds__(256) void uber1_kernel(
    const short* __restrict__ qh, const short* __restrict__ kh, const short* __restrict__ vT,
    const unsigned long long* __restrict__ bits, float* __restrict__ linvb,
    short* __restrict__ ctx, const short* __restrict__ WTo,
    const float* __restrict__ bo, const float* __restrict__ resid,
    float* __restrict__ out, float* __restrict__ attn)
{
    __shared__ __align__(16) short UB[36864];
    const int bid = blockIdx.x;
    if (bid < 512) {
        const int logical = (bid & 7) * 64 + (bid >> 3);
        body_attn(qh, kh, vT, bits, linvb, ctx, 1, logical, UB);
        return;
    }
    const int rem = bid - 512;
    if (rem < 128) {
        body_outproj(ctx, WTo, bo, resid, out, 0, rem & 15, rem >> 4, UB);
        return;
    }
    body_store(qh, kh, bits, linvb, attn, 0, rem - 128, UB);
}

// uber2: outproj(b1) [0,128) + store(b1) [128,2176) + ln(b0) [2176,4224)
__global__ __launch_bounds__(256) void uber2_kernel(
    const short* __restrict__ qh, const short* __restrict__ kh,
    const unsigned long long* __restrict__ bits, const float* __restrict__ linvb,
    const short* __restrict__ ctx, const short* __restrict__ WTo,
    const float* __restrict__ bo, const float* __restrict__ resid,
    float* __restrict__ out, float* __restrict__ attn,
    const float* __restrict__ gamma, const float* __restrict__ beta)
{
    __shared__ __align__(16) short UB[36864];
    const int bid = blockIdx.x;
    if (bid < 128) {
        body_outproj(ctx, WTo, bo, resid, out, 1, bid & 15, bid >> 4, UB);
        return;
    }
    if (bid < 2176) {
        body_store(qh, kh, bits, linvb, attn, 1, bid - 128, UB);
        return;
    }
    body_ln(out, gamma, beta, bid - 2176, (float*)UB);
}

// final LN for batch 1 rows
__global__ __launch_bounds__(256) void lnb_kernel(
    float* __restrict__ io, const float* __restrict__ g, const float* __restrict__ bta)
{
    __shared__ float sh[8];
    body_ln(io, g, bta, SS + blockIdx.x, sh);
}

// ===========================================================================
extern "C" void kernel_launch(void* const* d_in, const int* in_sizes, int n_in,
                              void* d_out, int out_size, void* d_ws, size_t ws_size,
                              hipStream_t stream)
{
    (void)in_sizes; (void)n_in; (void)out_size; (void)ws_size;
    const float* q     = (const float*)d_in[0];
    const float* k     = (const float*)d_in[1];
    const float* v     = (const float*)d_in[2];
    const int*   mask  = (const int*)d_in[3];
    const float* wq    = (const float*)d_in[4];
    const float* bq    = (const float*)d_in[5];
    const float* wk    = (const float*)d_in[6];
    const float* bk    = (const float*)d_in[7];
    const float* wv    = (const float*)d_in[8];
    const float* bv    = (const float*)d_in[9];
    const float* wo    = (const float*)d_in[10];
    const float* bo    = (const float*)d_in[11];
    const float* gamma = (const float*)d_in[12];
    const float* beta  = (const float*)d_in[13];

    float* out  = (float*)d_out;                    // [B,S,D]
    float* attn = out + (size_t)BB * SS * DD;       // [B,H,S,S]

    const size_t hsz = (size_t)BB * HH * SS * DKV;  // 4,194,304
    short* qhp = (short*)d_ws;
    short* khp = qhp + hsz;
    short* vTp = khp + hsz;                         // vT[b][h][d][s]
    short* ctx = vTp + hsz;
    unsigned long long* bits = (unsigned long long*)(ctx + hsz);       // 1 MB
    float* linvb = (float*)(bits + (size_t)BB * SS * (SS / 64));       // 256 KB
    short* wtq = (short*)(linvb + (size_t)BB * HH * SS);               // 4 x 2 MB
    short* wtk = wtq + (size_t)DD * DD;
    short* wtv = wtk + (size_t)DD * DD;
    short* wto = wtv + (size_t)DD * DD;
    short* qb  = wto + (size_t)DD * DD;                                // 3 x 8 MB
    short* kb2 = qb  + (size_t)BB * SS * DD;
    short* vb2 = kb2 + (size_t)BB * SS * DD;

    // L1: weight transpose + q/k/v bf16 conversion (both batches)
    dim3 gw(16, 16, 7);
    wtrans_kernel<<<gw, 256, 0, stream>>>(wq, wk, wv, wo, q, k, v,
                                          wtq, wtk, wtv, wto, qb, kb2, vb2);

    // L2: projections + mask pack, batch 0
    dim3 gg(16, 8, 4);
    proj3b_kernel<<<gg, 256, 0, stream>>>(qb, kb2, vb2, wtq, wtk, wtv, bq, bk, bv,
                                          qhp, khp, vTp, mask, bits, 0);

    // L3: attn(b0) || proj(b1)+pack(b1)
    uber0_kernel<<<1024, 256, 0, stream>>>(qb, kb2, vb2, wtq, wtk, wtv, bq, bk, bv,
                                           qhp, khp, vTp, mask, bits, linvb, ctx);

    // L4: attn(b1) || outproj(b0)+store(b0)
    uber1_kernel<<<2688, 256, 0, stream>>>(qhp, khp, vTp, bits, linvb, ctx,
                                           wto, bo, q, out, attn);

    // L5: outproj(b1)+store(b1) || ln(b0)
    uber2_kernel<<<4224, 256, 0, stream>>>(qhp, khp, bits, linvb, ctx,
                                           wto, bo, q, out, attn, gamma, beta);

    // L6: ln(b1)
    lnb_kernel<<<SS, 256, 0, stream>>>(out, gamma, beta);
}

// Round 12
// 372.433 us; speedup vs baseline: 1.0832x; 1.0832x over previous
//
#include <hip/hip_runtime.h>
#include <hip/hip_bf16.h>

#define BB 2
#define SS 2048
#define DD 1024
#define HH 16
#define DKV 64

typedef __attribute__((ext_vector_type(8))) short short8;
typedef __attribute__((ext_vector_type(4))) short short4_t;
typedef __attribute__((ext_vector_type(4))) float f32x4;

#define MFMA16(a, b, c) __builtin_amdgcn_mfma_f32_16x16x32_bf16(a, b, c, 0, 0, 0)

__device__ __forceinline__ short f2bf(float f) {
    __hip_bfloat16 h = __float2bfloat16(f);
    union { __hip_bfloat16 h; short s; } u;
    u.h = h;
    return u.s;
}

// ===========================================================================
// 512-thread phase bodies
// ===========================================================================

// mask bit-pack: 64 blocks/batch, 1024 words/block
__device__ __forceinline__ void body_pack8(
    const int* __restrict__ mask, unsigned long long* __restrict__ bits,
    int batch, int bid)
{
    const int t = threadIdx.x, lane = t & 63, wave = t >> 6;
    const int base = batch * 65536 + bid * 1024 + wave * 128;
    #pragma unroll 4
    for (int wi = base; wi < base + 128; ++wi) {
        const int mv = mask[(size_t)wi * 64 + lane];
        const unsigned long long bal = __ballot(mv != 0);
        if (lane == 0) bits[wi] = bal;
    }
}

// proj GEMM, 8 waves: 128x128 tile, wave = 64x32. zmode 2 -> vT layout.
__device__ __forceinline__ void body_proj8(
    const short* __restrict__ A, const short* __restrict__ WT,
    const float* __restrict__ bias, short* __restrict__ outp,
    int zmode, int batch, int bx, int by, short* lds)
{
    short (*As)[40] = (short(*)[40])lds;
    short (*Bs)[40] = (short(*)[40])(lds + 5120);
    const int t = threadIdx.x, lane = t & 63, wave = t >> 6;
    const int wm = wave >> 2, wn = wave & 3;       // 2 x 4 wave grid
    const int m0 = batch * SS + bx * 128, n0 = by * 128;
    const int lr = lane & 15, kb = (lane >> 4) * 8;
    const int row3 = t >> 2, kk3 = (t & 3) * 8;

    f32x4 acc[4][2] = {};
    for (int k0 = 0; k0 < DD; k0 += 32) {
        __syncthreads();
        *(short8*)&As[row3][kk3] = *(const short8*)(A  + (size_t)(m0 + row3) * DD + k0 + kk3);
        *(short8*)&Bs[row3][kk3] = *(const short8*)(WT + (size_t)(n0 + row3) * DD + k0 + kk3);
        __syncthreads();
        short8 af[4], bfr[2];
        #pragma unroll
        for (int i = 0; i < 4; i++) af[i]  = *(const short8*)&As[wm * 64 + i * 16 + lr][kb];
        #pragma unroll
        for (int j = 0; j < 2; j++) bfr[j] = *(const short8*)&Bs[wn * 32 + j * 16 + lr][kb];
        #pragma unroll
        for (int i = 0; i < 4; i++)
            #pragma unroll
            for (int j = 0; j < 2; j++)
                acc[i][j] = MFMA16(af[i], bfr[j], acc[i][j]);
    }

    if (zmode != 2) {
        #pragma unroll
        for (int j = 0; j < 2; j++) {
            const int col = n0 + wn * 32 + j * 16 + lr;
            const float bvv = bias[col];
            const int h = col >> 6, d = col & 63;
            #pragma unroll
            for (int i = 0; i < 4; i++) {
                #pragma unroll
                for (int r = 0; r < 4; r++) {
                    const int m = m0 + wm * 64 + i * 16 + (lane >> 4) * 4 + r;
                    const int b = m >> 11, s = m & (SS - 1);
                    outp[(((size_t)(b * HH + h)) * SS + s) * DKV + d] =
                        f2bf(acc[i][j][r] + bvv);
                }
            }
        }
    } else {
        #pragma unroll
        for (int j = 0; j < 2; j++) {
            const int col = n0 + wn * 32 + j * 16 + lr;
            const float bvv = bias[col];
            const int h = col >> 6, d = col & 63;
            #pragma unroll
            for (int i = 0; i < 4; i++) {
                const int m = m0 + wm * 64 + i * 16 + (lane >> 4) * 4;
                const int b = m >> 11, s = m & (SS - 1);
                short4_t pk;
                #pragma unroll
                for (int r = 0; r < 4; r++) pk[r] = f2bf(acc[i][j][r] + bvv);
                *(short4_t*)(outp + ((size_t)(b * HH + h) * DKV + d) * SS + s) = pk;
            }
        }
    }
}

// attention compute, 8 waves / 128 q-rows (byte-identical math to R10)
__device__ __forceinline__ void body_attn8(
    const short* __restrict__ qh, const short* __restrict__ kh,
    const short* __restrict__ vT, const unsigned long long* __restrict__ bits,
    float* __restrict__ linvb, short* __restrict__ ctx,
    int batch, int logical, short* lds)
{
    short (*Ks)[64][72] = (short(*)[64][72])lds;            // [2][64][72]
    short (*Vs)[64][72] = (short(*)[64][72])(lds + 9216);
    short (*Ps)[16][72] = (short(*)[16][72])(lds + 18432);  // [8][16][72]
    const int t = threadIdx.x, lane = t & 63, w = t >> 6;
    const int qt = logical & 15;
    const int h  = logical >> 4;
    const int bh = batch * HH + h;
    const int q0w = qt * 128 + w * 16;
    const size_t headbase = (size_t)bh * SS * DKV;
    const int lr = lane & 15, kb = (lane >> 4) * 8;
    const int rbase = (lane >> 4) * 4;

    const short* kbase = kh + headbase;
    const short* vbase = vT + (size_t)bh * DKV * SS;
    const unsigned long long* bitrow = bits + ((size_t)batch * SS + q0w) * (SS / 64);

    const int srow = t >> 3, sc8 = (t & 7) * 8;
    const short* kstg = kbase + (size_t)srow * DKV + sc8;
    const short* vstg = vbase + (size_t)srow * SS + sc8;

    const short* qrp = qh + headbase + (size_t)(q0w + lr) * DKV;
    const short8 aq0 = *(const short8*)(qrp + kb);
    const short8 aq1 = *(const short8*)(qrp + 32 + kb);

    float lsum[4] = {0.f, 0.f, 0.f, 0.f};
    f32x4 cacc[4] = {};

    short8 kreg = *(const short8*)(kstg);
    short8 vreg = *(const short8*)(vstg);
    *(short8*)&Ks[0][srow][sc8] = kreg;
    *(short8*)&Vs[0][srow][sc8] = vreg;
    __syncthreads();
    for (int kt = 0; kt < 32; ++kt) {
        const int cur = kt & 1;
        if (kt + 1 < 32) {
            kreg = *(const short8*)(kstg + (size_t)(kt + 1) * 64 * DKV);
            vreg = *(const short8*)(vstg + (size_t)(kt + 1) * 64);
        }
        f32x4 sc[4];
        __builtin_amdgcn_s_setprio(1);
        #pragma unroll
        for (int fc = 0; fc < 4; ++fc) {
            short8 bk0 = *(const short8*)&Ks[cur][fc * 16 + lr][kb];
            short8 bk1 = *(const short8*)&Ks[cur][fc * 16 + lr][32 + kb];
            f32x4 s = {0.f, 0.f, 0.f, 0.f};
            s = MFMA16(aq0, bk0, s);
            s = MFMA16(aq1, bk1, s);
            sc[fc] = s;
        }
        __builtin_amdgcn_s_setprio(0);
        unsigned long long mw[4];
        #pragma unroll
        for (int r = 0; r < 4; ++r)
            mw[r] = bitrow[(size_t)(rbase + r) * (SS / 64) + kt];
        #pragma unroll
        for (int fc = 0; fc < 4; ++fc)
            #pragma unroll
            for (int r = 0; r < 4; ++r) {
                const bool masked = (mw[r] >> (fc * 16 + lr)) & 1ull;
                const float p = masked ? 0.f : __expf(sc[fc][r] * 0.125f);
                lsum[r] += p;
                Ps[w][rbase + r][fc * 16 + lr] = f2bf(p);
            }
        short8 ap0 = *(const short8*)&Ps[w][lr][kb];
        short8 ap1 = *(const short8*)&Ps[w][lr][32 + kb];
        __builtin_amdgcn_s_setprio(1);
        #pragma unroll
        for (int fd = 0; fd < 4; ++fd) {
            short8 bv0 = *(const short8*)&Vs[cur][fd * 16 + lr][kb];
            short8 bv1 = *(const short8*)&Vs[cur][fd * 16 + lr][32 + kb];
            cacc[fd] = MFMA16(ap0, bv0, cacc[fd]);
            cacc[fd] = MFMA16(ap1, bv1, cacc[fd]);
        }
        __builtin_amdgcn_s_setprio(0);
        if (kt + 1 < 32) {
            *(short8*)&Ks[cur ^ 1][srow][sc8] = kreg;
            *(short8*)&Vs[cur ^ 1][srow][sc8] = vreg;
        }
        __syncthreads();
    }
    #pragma unroll
    for (int r = 0; r < 4; r++) {
        float s = lsum[r];
        s += __shfl_xor(s, 1);
        s += __shfl_xor(s, 2);
        s += __shfl_xor(s, 4);
        s += __shfl_xor(s, 8);
        lsum[r] = s;
    }
    float linv[4];
    #pragma unroll
    for (int r = 0; r < 4; r++) linv[r] = 1.f / lsum[r];

    if (lr == 0) {
        #pragma unroll
        for (int r = 0; r < 4; r++)
            linvb[(size_t)bh * SS + q0w + rbase + r] = linv[r];
    }
    #pragma unroll
    for (int fd = 0; fd < 4; ++fd)
        #pragma unroll
        for (int r = 0; r < 4; r++) {
            const int qrow = q0w + rbase + r;
            ctx[((size_t)batch * SS + qrow) * DD + h * DKV + fd * 16 + lr] =
                f2bf(cacc[fd][r] * linv[r]);
        }
}

// output GEMM, 8 waves: 128x128 tile, wave = 64x32
__device__ __forceinline__ void body_outproj8(
    const short* __restrict__ Actx, const short* __restrict__ WT,
    const float* __restrict__ bias, const float* __restrict__ resid,
    float* __restrict__ out, int batch, int bx, int by, short* lds)
{
    short (*As)[40] = (short(*)[40])lds;
    short (*Bs)[40] = (short(*)[40])(lds + 5120);
    const int t = threadIdx.x, lane = t & 63, wave = t >> 6;
    const int wm = wave >> 2, wn = wave & 3;
    const int m0 = batch * SS + bx * 128, n0 = by * 128;
    const int lr = lane & 15, kb = (lane >> 4) * 8;
    const int row3 = t >> 2, kk3 = (t & 3) * 8;

    f32x4 acc[4][2] = {};
    for (int k0 = 0; k0 < DD; k0 += 32) {
        __syncthreads();
        *(short8*)&As[row3][kk3] = *(const short8*)(Actx + (size_t)(m0 + row3) * DD + k0 + kk3);
        *(short8*)&Bs[row3][kk3] = *(const short8*)(WT   + (size_t)(n0 + row3) * DD + k0 + kk3);
        __syncthreads();
        short8 af[4], bfr[2];
        #pragma unroll
        for (int i = 0; i < 4; i++) af[i]  = *(const short8*)&As[wm * 64 + i * 16 + lr][kb];
        #pragma unroll
        for (int j = 0; j < 2; j++) bfr[j] = *(const short8*)&Bs[wn * 32 + j * 16 + lr][kb];
        #pragma unroll
        for (int i = 0; i < 4; i++)
            #pragma unroll
            for (int j = 0; j < 2; j++)
                acc[i][j] = MFMA16(af[i], bfr[j], acc[i][j]);
    }
    #pragma unroll
    for (int j = 0; j < 2; j++) {
        const int col = n0 + wn * 32 + j * 16 + lr;
        const float bvv = bias[col];
        #pragma unroll
        for (int i = 0; i < 4; i++) {
            #pragma unroll
            for (int r = 0; r < 4; r++) {
                const int m = m0 + wm * 64 + i * 16 + (lane >> 4) * 4 + r;
                out[(size_t)m * DD + col] = acc[i][j][r] + bvv + resid[(size_t)m * DD + col];
            }
        }
    }
}

// attn store, 8 waves: 128q x 512k tile
__device__ __forceinline__ void body_store8(
    const short* __restrict__ qh, const short* __restrict__ kh,
    const unsigned long long* __restrict__ bits, const float* __restrict__ linvb,
    float* __restrict__ attn, int batch, int sb, short* lds)
{
    short (*Ks)[72] = (short(*)[72])lds;   // 512 x 72
    const int t = threadIdx.x, lane = t & 63, w = t >> 6;
    const int qt = sb & 15;
    const int kc = (sb >> 4) & 3;
    const int hh = sb >> 6;
    const int bh = batch * HH + hh;
    const int q0w = qt * 128 + w * 16;
    const int k0c = kc * 512;
    const size_t headbase = (size_t)bh * SS * DKV;
    const int lr = lane & 15, kb = (lane >> 4) * 8;
    const int rbase = (lane >> 4) * 4;

    {
        const short* kb2 = kh + headbase + (size_t)k0c * DKV;
        const int c8 = (t & 7) * 8;
        #pragma unroll
        for (int sweep = 0; sweep < 8; ++sweep) {
            const int row = (t >> 3) + sweep * 64;
            *(short8*)&Ks[row][c8] = *(const short8*)(kb2 + (size_t)row * DKV + c8);
        }
    }

    const short* qrp = qh + headbase + (size_t)(q0w + lr) * DKV;
    const short8 aq0 = *(const short8*)(qrp + kb);
    const short8 aq1 = *(const short8*)(qrp + 32 + kb);

    float linv[4];
    #pragma unroll
    for (int r = 0; r < 4; ++r)
        linv[r] = linvb[(size_t)bh * SS + q0w + rbase + r];

    const unsigned long long* bitrow = bits + ((size_t)batch * SS + q0w) * (SS / 64);
    float* arow = attn + ((size_t)bh * SS + q0w) * SS + k0c;

    __syncthreads();

    for (int g = 0; g < 8; ++g) {
        unsigned long long mw[4];
        #pragma unroll
        for (int r = 0; r < 4; ++r)
            mw[r] = bitrow[(size_t)(rbase + r) * (SS / 64) + kc * 8 + g];
        #pragma unroll
        for (int fc = 0; fc < 4; ++fc) {
            const int col = g * 64 + fc * 16;
            short8 bk0 = *(const short8*)&Ks[col + lr][kb];
            short8 bk1 = *(const short8*)&Ks[col + lr][32 + kb];
            f32x4 s = {0.f, 0.f, 0.f, 0.f};
            s = MFMA16(aq0, bk0, s);
            s = MFMA16(aq1, bk1, s);
            #pragma unroll
            for (int r = 0; r < 4; ++r) {
                const bool masked = (mw[r] >> (fc * 16 + lr)) & 1ull;
                const float p = masked ? 0.f : __expf(s[r] * 0.125f) * linv[r];
                arow[(size_t)(rbase + r) * SS + col + lr] = p;
            }
        }
    }
}

// ===========================================================================
// Kernels
// ===========================================================================

// z=0..3: W -> WT bf16; z=4..6: q/k/v fp32 -> bf16 (unchanged R10)
__global__ __launch_bounds__(256) void wtrans_kernel(
    const float* __restrict__ w0, const float* __restrict__ w1,
    const float* __restrict__ w2, const float* __restrict__ w3,
    const float* __restrict__ qf, const float* __restrict__ kf, const float* __restrict__ vf,
    short* __restrict__ o0, short* __restrict__ o1,
    short* __restrict__ o2, short* __restrict__ o3,
    short* __restrict__ oq, short* __restrict__ ok, short* __restrict__ ov)
{
    const int z = blockIdx.z;
    const int t = threadIdx.x;
    if (z >= 4) {
        const float* src = (z == 4) ? qf : (z == 5) ? kf : vf;
        short* dst = (z == 4) ? oq : (z == 5) ? ok : ov;
        size_t idx = ((size_t)(blockIdx.y * 16 + blockIdx.x) * 256 + t) * 8;
        #pragma unroll
        for (int it = 0; it < 8; ++it, idx += 524288) {
            float4 a = *(const float4*)(src + idx);
            float4 b = *(const float4*)(src + idx + 4);
            short8 p = { f2bf(a.x), f2bf(a.y), f2bf(a.z), f2bf(a.w),
                         f2bf(b.x), f2bf(b.y), f2bf(b.z), f2bf(b.w) };
            *(short8*)(dst + idx) = p;
        }
        return;
    }
    const float* W = (z == 0) ? w0 : (z == 1) ? w1 : (z == 2) ? w2 : w3;
    short* O = (z == 0) ? o0 : (z == 1) ? o1 : (z == 2) ? o2 : o3;
    __shared__ short T[64][72];
    const int k0 = blockIdx.x * 64, n0 = blockIdx.y * 64;
    const int row = t >> 2, c = (t & 3) * 16;
    const float* src = W + (size_t)(k0 + row) * DD + n0 + c;
    #pragma unroll
    for (int i = 0; i < 16; i += 4) {
        float4 f = *(const float4*)(src + i);
        T[c + i + 0][row] = f2bf(f.x);
        T[c + i + 1][row] = f2bf(f.y);
        T[c + i + 2][row] = f2bf(f.z);
        T[c + i + 3][row] = f2bf(f.w);
    }
    __syncthreads();
    const int nr = t >> 2, kc = (t & 3) * 16;
    *(short8*)(O + (size_t)(n0 + nr) * DD + k0 + kc)     = *(const short8*)&T[nr][kc];
    *(short8*)(O + (size_t)(n0 + nr) * DD + k0 + kc + 8) = *(const short8*)&T[nr][kc + 8];
}

// L2: proj(b0) [0,384) + pack(b0) [384,448)
__global__ __launch_bounds__(512) void pipe2_kernel(
    const short* __restrict__ qb, const short* __restrict__ kbf, const short* __restrict__ vbf,
    const short* __restrict__ WT0, const short* __restrict__ WT1, const short* __restrict__ WT2,
    const float* __restrict__ bq, const float* __restrict__ bk, const float* __restrict__ bv,
    short* __restrict__ qh, short* __restrict__ kh, short* __restrict__ vT,
    const int* __restrict__ mask, unsigned long long* __restrict__ bits)
{
    __shared__ __align__(16) short UB[10240];
    const int bid = blockIdx.x;
    if (bid < 384) {
        const int z = bid / 128, local = bid % 128;
        const short* A  = (z == 0) ? qb : (z == 1) ? kbf : vbf;
        const short* WT = (z == 0) ? WT0 : (z == 1) ? WT1 : WT2;
        const float* bias = (z == 0) ? bq : (z == 1) ? bk : bv;
        short* outp = (z == 0) ? qh : (z == 1) ? kh : vT;
        body_proj8(A, WT, bias, outp, z, 0, local & 15, local >> 4, UB);
        return;
    }
    body_pack8(mask, bits, 0, bid - 384);
}

// L3: attn(b0) [0,256) + proj(b1) [256,640) + pack(b1) [640,704)
__global__ __launch_bounds__(512) void pipe3_kernel(
    const short* __restrict__ qb, const short* __restrict__ kbf, const short* __restrict__ vbf,
    const short* __restrict__ WT0, const short* __restrict__ WT1, const short* __restrict__ WT2,
    const float* __restrict__ bq, const float* __restrict__ bk, const float* __restrict__ bv,
    short* __restrict__ qh, short* __restrict__ kh, short* __restrict__ vT,
    const int* __restrict__ mask, unsigned long long* __restrict__ bits,
    float* __restrict__ linvb, short* __restrict__ ctx)
{
    __shared__ __align__(16) short UB[27648];
    const int bid = blockIdx.x;
    if (bid < 256) {
        const int logical = (bid & 7) * 32 + (bid >> 3);   // XCD grouping
        body_attn8(qh, kh, vT, bits, linvb, ctx, 0, logical, UB);
        return;
    }
    const int rem = bid - 256;
    if (rem < 384) {
        const int z = rem / 128, local = rem % 128;
        const short* A  = (z == 0) ? qb : (z == 1) ? kbf : vbf;
        const short* WT = (z == 0) ? WT0 : (z == 1) ? WT1 : WT2;
        const float* bias = (z == 0) ? bq : (z == 1) ? bk : bv;
        short* outp = (z == 0) ? qh : (z == 1) ? kh : vT;
        body_proj8(A, WT, bias, outp, z, 1, local & 15, local >> 4, UB);
        return;
    }
    body_pack8(mask, bits, 1, rem - 384);
}

// L4: attn(b1) [0,256) + store(b0) [256,1280)
__global__ __launch_bounds__(512) void pipe4_kernel(
    const short* __restrict__ qh, const short* __restrict__ kh, const short* __restrict__ vT,
    const unsigned long long* __restrict__ bits, float* __restrict__ linvb,
    short* __restrict__ ctx, float* __restrict__ attn)
{
    __shared__ __align__(16) short UB[36864];
    const int bid = blockIdx.x;
    if (bid < 256) {
        const int logical = (bid & 7) * 32 + (bid >> 3);
        body_attn8(qh, kh, vT, bits, linvb, ctx, 1, logical, UB);
        return;
    }
    body_store8(qh, kh, bits, linvb, attn, 0, bid - 256, UB);
}

// L5: outproj(b0,b1) [0,256) + store(b1) [256,1280)
__global__ __launch_bounds__(512) void pipe5_kernel(
    const short* __restrict__ qh, const short* __restrict__ kh,
    const unsigned long long* __restrict__ bits, const float* __restrict__ linvb,
    const short* __restrict__ ctx, const short* __restrict__ WTo,
    const float* __restrict__ bo, const float* __restrict__ resid,
    float* __restrict__ out, float* __restrict__ attn)
{
    __shared__ __align__(16) short UB[36864];
    const int bid = blockIdx.x;
    if (bid < 256) {
        const int batch = bid >> 7, local = bid & 127;
        body_outproj8(ctx, WTo, bo, resid, out, batch, local & 15, local >> 4, UB);
        return;
    }
    body_store8(qh, kh, bits, linvb, attn, 1, bid - 256, UB);
}

// L6: LayerNorm, both batches
__global__ __launch_bounds__(256) void ln_kernel(
    float* __restrict__ io, const float* __restrict__ g, const float* __restrict__ bta)
{
    const int row = blockIdx.x;
    const int t = threadIdx.x;
    float* p = io + (size_t)row * DD;
    float4 x = *(float4*)(p + t * 4);
    float s  = x.x + x.y + x.z + x.w;
    float s2 = x.x * x.x + x.y * x.y + x.z * x.z + x.w * x.w;
    #pragma unroll
    for (int off = 32; off; off >>= 1) {
        s  += __shfl_xor(s, off);
        s2 += __shfl_xor(s2, off);
    }
    __shared__ float as_[4], bs_[4];
    const int w = t >> 6, l = t & 63;
    if (!l) { as_[w] = s; bs_[w] = s2; }
    __syncthreads();
    s  = as_[0] + as_[1] + as_[2] + as_[3];
    s2 = bs_[0] + bs_[1] + bs_[2] + bs_[3];
    const float mu  = s * (1.f / DD);
    const float var = s2 * (1.f / DD) - mu * mu;
    const float rs  = rsqrtf(var + 1e-5f);
    float4 gv = *(const float4*)(g + t * 4);
    float4 bv = *(const float4*)(bta + t * 4);
    float4 o;
    o.x = (x.x - mu) * rs * gv.x + bv.x;
    o.y = (x.y - mu) * rs * gv.y + bv.y;
    o.z = (x.z - mu) * rs * gv.z + bv.z;
    o.w = (x.w - mu) * rs * gv.w + bv.w;
    *(float4*)(p + t * 4) = o;
}

// ===========================================================================
extern "C" void kernel_launch(void* const* d_in, const int* in_sizes, int n_in,
                              void* d_out, int out_size, void* d_ws, size_t ws_size,
                              hipStream_t stream)
{
    (void)in_sizes; (void)n_in; (void)out_size; (void)ws_size;
    const float* q     = (const float*)d_in[0];
    const float* k     = (const float*)d_in[1];
    const float* v     = (const float*)d_in[2];
    const int*   mask  = (const int*)d_in[3];
    const float* wq    = (const float*)d_in[4];
    const float* bq    = (const float*)d_in[5];
    const float* wk    = (const float*)d_in[6];
    const float* bk    = (const float*)d_in[7];
    const float* wv    = (const float*)d_in[8];
    const float* bv    = (const float*)d_in[9];
    const float* wo    = (const float*)d_in[10];
    const float* bo    = (const float*)d_in[11];
    const float* gamma = (const float*)d_in[12];
    const float* beta  = (const float*)d_in[13];

    float* out  = (float*)d_out;                    // [B,S,D]
    float* attn = out + (size_t)BB * SS * DD;       // [B,H,S,S]

    const size_t hsz = (size_t)BB * HH * SS * DKV;  // 4,194,304
    short* qhp = (short*)d_ws;
    short* khp = qhp + hsz;
    short* vTp = khp + hsz;                         // vT[b][h][d][s]
    short* ctx = vTp + hsz;
    unsigned long long* bits = (unsigned long long*)(ctx + hsz);       // 1 MB
    float* linvb = (float*)(bits + (size_t)BB * SS * (SS / 64));       // 256 KB
    short* wtq = (short*)(linvb + (size_t)BB * HH * SS);               // 4 x 2 MB
    short* wtk = wtq + (size_t)DD * DD;
    short* wtv = wtk + (size_t)DD * DD;
    short* wto = wtv + (size_t)DD * DD;
    short* qb  = wto + (size_t)DD * DD;                                // 3 x 8 MB
    short* kb2 = qb  + (size_t)BB * SS * DD;
    short* vb2 = kb2 + (size_t)BB * SS * DD;

    // L1: weight transpose + q/k/v bf16 conversion (both batches)
    dim3 gw(16, 16, 7);
    wtrans_kernel<<<gw, 256, 0, stream>>>(wq, wk, wv, wo, q, k, v,
                                          wtq, wtk, wtv, wto, qb, kb2, vb2);

    // L2: proj(b0) + pack(b0)
    pipe2_kernel<<<448, 512, 0, stream>>>(qb, kb2, vb2, wtq, wtk, wtv, bq, bk, bv,
                                          qhp, khp, vTp, mask, bits);

    // L3: attn(b0) || proj(b1) + pack(b1)
    pipe3_kernel<<<704, 512, 0, stream>>>(qb, kb2, vb2, wtq, wtk, wtv, bq, bk, bv,
                                          qhp, khp, vTp, mask, bits, linvb, ctx);

    // L4: attn(b1) || store(b0)
    pipe4_kernel<<<1280, 512, 0, stream>>>(qhp, khp, vTp, bits, linvb, ctx, attn);

    // L5: outproj(b0,b1) || store(b1)
    pipe5_kernel<<<1280, 512, 0, stream>>>(qhp, khp, bits, linvb, ctx,
                                           wto, bo, q, out, attn);

    // L6: ln (both batches)
    ln_kernel<<<BB * SS, 256, 0, stream>>>(out, gamma, beta);
}

// Round 13
// 349.896 us; speedup vs baseline: 1.1529x; 1.0644x over previous
//
#include <hip/hip_runtime.h>
#include <hip/hip_bf16.h>

#define BB 2
#define SS 2048
#define DD 1024
#define HH 16
#define DKV 64

typedef __attribute__((ext_vector_type(8))) short short8;
typedef __attribute__((ext_vector_type(4))) short short4_t;
typedef __attribute__((ext_vector_type(4))) float f32x4;

#define MFMA16(a, b, c) __builtin_amdgcn_mfma_f32_16x16x32_bf16(a, b, c, 0, 0, 0)

__device__ __forceinline__ short f2bf(float f) {
    __hip_bfloat16 h = __float2bfloat16(f);
    union { __hip_bfloat16 h; short s; } u;
    u.h = h;
    return u.s;
}

// ---------------------------------------------------------------------------
// z=0..3: W[k][n] fp32 -> WT[n][k] bf16.  z=4..6: q/k/v fp32 -> bf16 copy.
// ---------------------------------------------------------------------------
__global__ __launch_bounds__(256) void wtrans_kernel(
    const float* __restrict__ w0, const float* __restrict__ w1,
    const float* __restrict__ w2, const float* __restrict__ w3,
    const float* __restrict__ qf, const float* __restrict__ kf, const float* __restrict__ vf,
    short* __restrict__ o0, short* __restrict__ o1,
    short* __restrict__ o2, short* __restrict__ o3,
    short* __restrict__ oq, short* __restrict__ ok, short* __restrict__ ov)
{
    const int z = blockIdx.z;
    const int t = threadIdx.x;
    if (z >= 4) {
        const float* src = (z == 4) ? qf : (z == 5) ? kf : vf;
        short* dst = (z == 4) ? oq : (z == 5) ? ok : ov;
        size_t idx = ((size_t)(blockIdx.y * 16 + blockIdx.x) * 256 + t) * 8;
        #pragma unroll
        for (int it = 0; it < 8; ++it, idx += 524288) {
            float4 a = *(const float4*)(src + idx);
            float4 b = *(const float4*)(src + idx + 4);
            short8 p = { f2bf(a.x), f2bf(a.y), f2bf(a.z), f2bf(a.w),
                         f2bf(b.x), f2bf(b.y), f2bf(b.z), f2bf(b.w) };
            *(short8*)(dst + idx) = p;
        }
        return;
    }
    const float* W = (z == 0) ? w0 : (z == 1) ? w1 : (z == 2) ? w2 : w3;
    short* O = (z == 0) ? o0 : (z == 1) ? o1 : (z == 2) ? o2 : o3;
    __shared__ short T[64][72];
    const int k0 = blockIdx.x * 64, n0 = blockIdx.y * 64;
    const int row = t >> 2, c = (t & 3) * 16;
    const float* src = W + (size_t)(k0 + row) * DD + n0 + c;
    #pragma unroll
    for (int i = 0; i < 16; i += 4) {
        float4 f = *(const float4*)(src + i);
        T[c + i + 0][row] = f2bf(f.x);
        T[c + i + 1][row] = f2bf(f.y);
        T[c + i + 2][row] = f2bf(f.z);
        T[c + i + 3][row] = f2bf(f.w);
    }
    __syncthreads();
    const int nr = t >> 2, kc = (t & 3) * 16;
    *(short8*)(O + (size_t)(n0 + nr) * DD + k0 + kc)     = *(const short8*)&T[nr][kc];
    *(short8*)(O + (size_t)(n0 + nr) * DD + k0 + kc + 8) = *(const short8*)&T[nr][kc + 8];
}

// ---------------------------------------------------------------------------
// Fused projection GEMMs + mask pack. A and B both pre-converted bf16.
// z=0: mask bit-pack; z=1,2 -> q,k [b][h][s][64]; z=3 -> vT[b][h][d][s].
// ---------------------------------------------------------------------------
__global__ __launch_bounds__(256) void proj3_kernel(
    const short* __restrict__ A0, const short* __restrict__ A1, const short* __restrict__ A2,
    const short* __restrict__ WT0, const short* __restrict__ WT1, const short* __restrict__ WT2,
    const float* __restrict__ bq, const float* __restrict__ bk, const float* __restrict__ bv,
    __hip_bfloat16* __restrict__ o0, __hip_bfloat16* __restrict__ o1, __hip_bfloat16* __restrict__ o2,
    const int* __restrict__ mask, unsigned long long* __restrict__ bits)
{
    const int t = threadIdx.x;
    const int lane = t & 63;
    const int wave = t >> 6;

    if (blockIdx.z == 0) {
        const int bid = blockIdx.y * 32 + blockIdx.x;
        const int base = bid * 512 + wave * 128;
        #pragma unroll 4
        for (int wi = base; wi < base + 128; ++wi) {
            const int mv = mask[(size_t)wi * 64 + lane];
            const unsigned long long bal = __ballot(mv != 0);
            if (lane == 0) bits[wi] = bal;
        }
        return;
    }

    const int z = blockIdx.z - 1;
    const short* A  = (z == 0) ? A0 : (z == 1) ? A1 : A2;
    const short* WT = (z == 0) ? WT0 : (z == 1) ? WT1 : WT2;
    const float* bias = (z == 0) ? bq : (z == 1) ? bk : bv;
    __hip_bfloat16* outh = (z == 0) ? o0 : (z == 1) ? o1 : o2;

    __shared__ __align__(16) short As[128][40];
    __shared__ __align__(16) short Bs[128][40];  // Bs[col][k]
    const int wm = wave >> 1, wn = wave & 1;
    const int m0 = blockIdx.x * 128, n0 = blockIdx.y * 128;
    const int lr = lane & 15;
    const int kb = (lane >> 4) * 8;
    const int row2 = t >> 1, kk2 = (t & 1) * 16;

    f32x4 acc[4][4] = {};

    for (int k0 = 0; k0 < DD; k0 += 32) {
        __syncthreads();
        {
            const short8* srca = (const short8*)(A + (size_t)(m0 + row2) * DD + k0 + kk2);
            *(short8*)&As[row2][kk2]     = srca[0];
            *(short8*)&As[row2][kk2 + 8] = srca[1];
        }
        {
            const short8* srcw = (const short8*)(WT + (size_t)(n0 + row2) * DD + k0 + kk2);
            *(short8*)&Bs[row2][kk2]     = srcw[0];
            *(short8*)&Bs[row2][kk2 + 8] = srcw[1];
        }
        __syncthreads();
        short8 af[4], bfr[4];
        #pragma unroll
        for (int i = 0; i < 4; i++) af[i]  = *(const short8*)&As[wm * 64 + i * 16 + lr][kb];
        #pragma unroll
        for (int j = 0; j < 4; j++) bfr[j] = *(const short8*)&Bs[wn * 64 + j * 16 + lr][kb];
        #pragma unroll
        for (int i = 0; i < 4; i++)
            #pragma unroll
            for (int j = 0; j < 4; j++)
                acc[i][j] = MFMA16(af[i], bfr[j], acc[i][j]);
    }

    if (z != 2) {
        #pragma unroll
        for (int j = 0; j < 4; j++) {
            const int col = n0 + wn * 64 + j * 16 + lr;
            const float bvv = bias[col];
            const int h = col >> 6, d = col & 63;
            #pragma unroll
            for (int i = 0; i < 4; i++) {
                #pragma unroll
                for (int r = 0; r < 4; r++) {
                    const int m = m0 + wm * 64 + i * 16 + (lane >> 4) * 4 + r;
                    const int b = m >> 11, s = m & (SS - 1);
                    outh[(((size_t)(b * HH + h)) * SS + s) * DKV + d] =
                        __float2bfloat16(acc[i][j][r] + bvv);
                }
            }
        }
    } else {
        short* vT = (short*)outh;
        #pragma unroll
        for (int j = 0; j < 4; j++) {
            const int col = n0 + wn * 64 + j * 16 + lr;
            const float bvv = bias[col];
            const int h = col >> 6, d = col & 63;
            #pragma unroll
            for (int i = 0; i < 4; i++) {
                const int m = m0 + wm * 64 + i * 16 + (lane >> 4) * 4;
                const int b = m >> 11, s = m & (SS - 1);
                short4_t pk;
                #pragma unroll
                for (int r = 0; r < 4; r++) pk[r] = f2bf(acc[i][j][r] + bvv);
                *(short4_t*)(vT + ((size_t)(b * HH + h) * DKV + d) * SS + s) = pk;
            }
        }
    }
}

// ---------------------------------------------------------------------------
// Attention kernel A (compute): QK + exp(unnorm) + row-sums + PV.
// Prefetch distance 2: load tile kt+2 while computing kt and LDS-writing kt+1.
// ---------------------------------------------------------------------------
__global__ __launch_bounds__(512) void attn_compute_kernel(
    const __hip_bfloat16* __restrict__ qh, const __hip_bfloat16* __restrict__ kh,
    const __hip_bfloat16* __restrict__ vT, const unsigned long long* __restrict__ bits,
    float* __restrict__ linvb, __hip_bfloat16* __restrict__ ctx)
{
    __shared__ __align__(16) short Ks[2][64][72];
    __shared__ __align__(16) short Vs[2][64][72];
    __shared__ __align__(16) short Ps[8][16][72];
    const int t = threadIdx.x, lane = t & 63, w = t >> 6;

    const int logical = (blockIdx.x & 7) * 64 + (blockIdx.x >> 3);
    const int qt = logical & 15;
    const int bh = logical >> 4;
    const int h = bh & (HH - 1);
    const int b = bh >> 4;
    const int q0w = qt * 128 + w * 16;
    const size_t headbase = (size_t)bh * SS * DKV;
    const int lr = lane & 15;
    const int kb = (lane >> 4) * 8;
    const int rbase = (lane >> 4) * 4;

    const short* kbase = (const short*)kh + headbase;
    const short* vbase = (const short*)vT + (size_t)bh * DKV * SS;
    const unsigned long long* bitrow = bits + ((size_t)b * SS + q0w) * (SS / 64);

    const int srow = t >> 3, sc8 = (t & 7) * 8;
    const short* kstg = kbase + (size_t)srow * DKV + sc8;
    const short* vstg = vbase + (size_t)srow * SS + sc8;

    const short* qrp = (const short*)qh + headbase + (size_t)(q0w + lr) * DKV;
    const short8 aq0 = *(const short8*)(qrp + kb);
    const short8 aq1 = *(const short8*)(qrp + 32 + kb);

    float lsum[4] = {0.f, 0.f, 0.f, 0.f};
    f32x4 cacc[4] = {};

    // per-tile compute body (cur = LDS buffer holding tile kt)
    auto compute_tile = [&](int kt, int cur) {
        f32x4 sc[4];
        __builtin_amdgcn_s_setprio(1);
        #pragma unroll
        for (int fc = 0; fc < 4; ++fc) {
            short8 bk0 = *(const short8*)&Ks[cur][fc * 16 + lr][kb];
            short8 bk1 = *(const short8*)&Ks[cur][fc * 16 + lr][32 + kb];
            f32x4 s = {0.f, 0.f, 0.f, 0.f};
            s = MFMA16(aq0, bk0, s);
            s = MFMA16(aq1, bk1, s);
            sc[fc] = s;
        }
        __builtin_amdgcn_s_setprio(0);
        unsigned long long mw[4];
        #pragma unroll
        for (int r = 0; r < 4; ++r)
            mw[r] = bitrow[(size_t)(rbase + r) * (SS / 64) + kt];
        #pragma unroll
        for (int fc = 0; fc < 4; ++fc)
            #pragma unroll
            for (int r = 0; r < 4; ++r) {
                const bool masked = (mw[r] >> (fc * 16 + lr)) & 1ull;
                const float p = masked ? 0.f : __expf(sc[fc][r] * 0.125f);
                lsum[r] += p;
                Ps[w][rbase + r][fc * 16 + lr] = f2bf(p);
            }
        short8 ap0 = *(const short8*)&Ps[w][lr][kb];
        short8 ap1 = *(const short8*)&Ps[w][lr][32 + kb];
        __builtin_amdgcn_s_setprio(1);
        #pragma unroll
        for (int fd = 0; fd < 4; ++fd) {
            short8 bv0 = *(const short8*)&Vs[cur][fd * 16 + lr][kb];
            short8 bv1 = *(const short8*)&Vs[cur][fd * 16 + lr][32 + kb];
            cacc[fd] = MFMA16(ap0, bv0, cacc[fd]);
            cacc[fd] = MFMA16(ap1, bv1, cacc[fd]);
        }
        __builtin_amdgcn_s_setprio(0);
    };

    // prologue: tile0 -> LDS[0]; tile1 -> reg set B
    short8 kA, vA, kB, vB;
    kA = *(const short8*)(kstg);
    vA = *(const short8*)(vstg);
    *(short8*)&Ks[0][srow][sc8] = kA;
    *(short8*)&Vs[0][srow][sc8] = vA;
    kB = *(const short8*)(kstg + (size_t)64 * DKV);
    vB = *(const short8*)(vstg + 64);
    __syncthreads();

    #pragma unroll 1
    for (int ktp = 0; ktp < 16; ++ktp) {
        const int kt0 = 2 * ktp;
        // ---- even tile kt0 (LDS[0]); set B holds kt0+1; set A free
        if (kt0 + 2 < 32) {
            kA = *(const short8*)(kstg + (size_t)(kt0 + 2) * 64 * DKV);
            vA = *(const short8*)(vstg + (size_t)(kt0 + 2) * 64);
        }
        compute_tile(kt0, 0);
        *(short8*)&Ks[1][srow][sc8] = kB;   // write tile kt0+1
        *(short8*)&Vs[1][srow][sc8] = vB;
        __syncthreads();
        // ---- odd tile kt0+1 (LDS[1]); set A holds kt0+2; set B free
        const int kt1 = kt0 + 1;
        if (kt1 + 2 < 32) {
            kB = *(const short8*)(kstg + (size_t)(kt1 + 2) * 64 * DKV);
            vB = *(const short8*)(vstg + (size_t)(kt1 + 2) * 64);
        }
        compute_tile(kt1, 1);
        if (kt1 + 1 < 32) {
            *(short8*)&Ks[0][srow][sc8] = kA;   // write tile kt1+1
            *(short8*)&Vs[0][srow][sc8] = vA;
        }
        __syncthreads();
    }

    #pragma unroll
    for (int r = 0; r < 4; r++) {
        float s = lsum[r];
        s += __shfl_xor(s, 1);
        s += __shfl_xor(s, 2);
        s += __shfl_xor(s, 4);
        s += __shfl_xor(s, 8);
        lsum[r] = s;
    }
    float linv[4];
    #pragma unroll
    for (int r = 0; r < 4; r++) linv[r] = 1.f / lsum[r];

    if (lr == 0) {
        #pragma unroll
        for (int r = 0; r < 4; r++)
            linvb[(size_t)bh * SS + q0w + rbase + r] = linv[r];
    }

    #pragma unroll
    for (int fd = 0; fd < 4; ++fd)
        #pragma unroll
        for (int r = 0; r < 4; r++) {
            const int qrow = q0w + rbase + r;
            ctx[((size_t)b * SS + qrow) * DD + h * DKV + fd * 16 + lr] =
                __float2bfloat16(cacc[fd][r] * linv[r]);
        }
}

// ---------------------------------------------------------------------------
// Merged kernel: z=0 -> output GEMM (+bias+residual); z=1..16 -> attn store
// slices. One launch so the 537MB attn write drain overlaps the GEMM.
// ---------------------------------------------------------------------------
__global__ __launch_bounds__(256) void outstore_kernel(
    const __hip_bfloat16* __restrict__ Actx, const short* __restrict__ WT,
    const float* __restrict__ bias, const float* __restrict__ resid,
    float* __restrict__ out,
    const __hip_bfloat16* __restrict__ qh, const __hip_bfloat16* __restrict__ kh,
    const unsigned long long* __restrict__ bits, const float* __restrict__ linvb,
    float* __restrict__ attn)
{
    __shared__ __align__(16) short LDSBUF[36864];   // 72KB, unioned
    const int t = threadIdx.x, lane = t & 63, w = t >> 6;
    const int lr = lane & 15;
    const int kb = (lane >> 4) * 8;

    if (blockIdx.z == 0) {
        // ---------------- output GEMM ----------------
        short (*As)[40] = (short(*)[40])LDSBUF;
        short (*Bs)[40] = (short(*)[40])(LDSBUF + 5120);
        const int wave = w;
        const int wm = wave >> 1, wn = wave & 1;
        const int m0 = blockIdx.x * 128, n0 = blockIdx.y * 128;
        const int row2 = t >> 1, kk2 = (t & 1) * 16;

        f32x4 acc[4][4] = {};

        for (int k0 = 0; k0 < DD; k0 += 32) {
            __syncthreads();
            {
                const short8* src = (const short8*)((const short*)Actx + (size_t)(m0 + row2) * DD + k0 + kk2);
                *(short8*)&As[row2][kk2]     = src[0];
                *(short8*)&As[row2][kk2 + 8] = src[1];
            }
            {
                const short8* srcw = (const short8*)(WT + (size_t)(n0 + row2) * DD + k0 + kk2);
                *(short8*)&Bs[row2][kk2]     = srcw[0];
                *(short8*)&Bs[row2][kk2 + 8] = srcw[1];
            }
            __syncthreads();
            short8 af[4], bfr[4];
            #pragma unroll
            for (int i = 0; i < 4; i++) af[i]  = *(const short8*)&As[wm * 64 + i * 16 + lr][kb];
            #pragma unroll
            for (int j = 0; j < 4; j++) bfr[j] = *(const short8*)&Bs[wn * 64 + j * 16 + lr][kb];
            #pragma unroll
            for (int i = 0; i < 4; i++)
                #pragma unroll
                for (int j = 0; j < 4; j++)
                    acc[i][j] = MFMA16(af[i], bfr[j], acc[i][j]);
        }

        #pragma unroll
        for (int j = 0; j < 4; j++) {
            const int col = n0 + wn * 64 + j * 16 + lr;
            const float bvv = bias[col];
            #pragma unroll
            for (int i = 0; i < 4; i++) {
                #pragma unroll
                for (int r = 0; r < 4; r++) {
                    const int m = m0 + wm * 64 + i * 16 + (lane >> 4) * 4 + r;
                    out[(size_t)m * DD + col] = acc[i][j][r] + bvv + resid[(size_t)m * DD + col];
                }
            }
        }
        return;
    }

    // ---------------- attn store slice ----------------
    short (*Ks)[72] = (short(*)[72])LDSBUF;
    const int sb = (blockIdx.z - 1) * 256 + blockIdx.y * 32 + blockIdx.x;  // 0..4095
    const int qt = sb & 31;
    const int kc = (sb >> 5) & 3;
    const int bh = sb >> 7;
    const int b = bh >> 4;
    const int q0w = qt * 64 + w * 16;
    const int k0c = kc * 512;
    const size_t headbase = (size_t)bh * SS * DKV;
    const int Q4 = lane >> 4;
    const int rbase = Q4 * 4;

    {
        const short* kbase = (const short*)kh + headbase + (size_t)k0c * DKV;
        const int c8 = (t & 7) * 8;
        #pragma unroll
        for (int sweep = 0; sweep < 16; ++sweep) {
            const int row = (t >> 3) + sweep * 32;
            *(short8*)&Ks[row][c8] = *(const short8*)(kbase + (size_t)row * DKV + c8);
        }
    }

    const short* qrp = (const short*)qh + headbase + (size_t)(q0w + lr) * DKV;
    const short8 aq0 = *(const short8*)(qrp + kb);
    const short8 aq1 = *(const short8*)(qrp + 32 + kb);

    float linv[4];
    #pragma unroll
    for (int r = 0; r < 4; ++r)
        linv[r] = linvb[(size_t)bh * SS + q0w + rbase + r];

    const unsigned long long* bitrow = bits + ((size_t)b * SS + q0w) * (SS / 64);
    float* arow = attn + ((size_t)bh * SS + q0w) * SS + k0c;

    __syncthreads();

    for (int g = 0; g < 8; ++g) {
        unsigned long long mw[4];
        #pragma unroll
        for (int r = 0; r < 4; ++r)
            mw[r] = bitrow[(size_t)(rbase + r) * (SS / 64) + kc * 8 + g];
        #pragma unroll
        for (int fc = 0; fc < 4; ++fc) {
            const int col = g * 64 + fc * 16;
            short8 bk0 = *(const short8*)&Ks[col + lr][kb];
            short8 bk1 = *(const short8*)&Ks[col + lr][32 + kb];
            f32x4 s = {0.f, 0.f, 0.f, 0.f};
            s = MFMA16(aq0, bk0, s);
            s = MFMA16(aq1, bk1, s);
            #pragma unroll
            for (int r = 0; r < 4; ++r) {
                const bool masked = (mw[r] >> (fc * 16 + lr)) & 1ull;
                const float p = masked ? 0.f : __expf(s[r] * 0.125f) * linv[r];
                arow[(size_t)(rbase + r) * SS + col + lr] = p;
            }
        }
    }
}

// ---------------------------------------------------------------------------
// LayerNorm in place on out[4096][1024], biased var, eps=1e-5
// ---------------------------------------------------------------------------
__global__ __launch_bounds__(256) void ln_kernel(
    float* __restrict__ io, const float* __restrict__ g, const float* __restrict__ bta)
{
    const int row = blockIdx.x;
    const int t = threadIdx.x;
    float* p = io + (size_t)row * DD;
    float4 x = *(float4*)(p + t * 4);
    float s  = x.x + x.y + x.z + x.w;
    float s2 = x.x * x.x + x.y * x.y + x.z * x.z + x.w * x.w;
    #pragma unroll
    for (int off = 32; off; off >>= 1) {
        s  += __shfl_xor(s, off);
        s2 += __shfl_xor(s2, off);
    }
    __shared__ float as_[4], bs_[4];
    const int w = t >> 6, l = t & 63;
    if (!l) { as_[w] = s; bs_[w] = s2; }
    __syncthreads();
    s  = as_[0] + as_[1] + as_[2] + as_[3];
    s2 = bs_[0] + bs_[1] + bs_[2] + bs_[3];
    const float mu  = s * (1.f / DD);
    const float var = s2 * (1.f / DD) - mu * mu;
    const float rs  = rsqrtf(var + 1e-5f);
    float4 gv = *(const float4*)(g + t * 4);
    float4 bv = *(const float4*)(bta + t * 4);
    float4 o;
    o.x = (x.x - mu) * rs * gv.x + bv.x;
    o.y = (x.y - mu) * rs * gv.y + bv.y;
    o.z = (x.z - mu) * rs * gv.z + bv.z;
    o.w = (x.w - mu) * rs * gv.w + bv.w;
    *(float4*)(p + t * 4) = o;
}

// ---------------------------------------------------------------------------
extern "C" void kernel_launch(void* const* d_in, const int* in_sizes, int n_in,
                              void* d_out, int out_size, void* d_ws, size_t ws_size,
                              hipStream_t stream)
{
    (void)in_sizes; (void)n_in; (void)out_size; (void)ws_size;
    const float* q     = (const float*)d_in[0];
    const float* k     = (const float*)d_in[1];
    const float* v     = (const float*)d_in[2];
    const int*   mask  = (const int*)d_in[3];
    const float* wq    = (const float*)d_in[4];
    const float* bq    = (const float*)d_in[5];
    const float* wk    = (const float*)d_in[6];
    const float* bk    = (const float*)d_in[7];
    const float* wv    = (const float*)d_in[8];
    const float* bv    = (const float*)d_in[9];
    const float* wo    = (const float*)d_in[10];
    const float* bo    = (const float*)d_in[11];
    const float* gamma = (const float*)d_in[12];
    const float* beta  = (const float*)d_in[13];

    float* out  = (float*)d_out;                    // [B,S,D]
    float* attn = out + (size_t)BB * SS * DD;       // [B,H,S,S]

    const size_t hsz = (size_t)BB * HH * SS * DKV;  // 4,194,304
    __hip_bfloat16* qhp = (__hip_bfloat16*)d_ws;
    __hip_bfloat16* khp = qhp + hsz;
    __hip_bfloat16* vTp = khp + hsz;                // vT[b][h][d][s]
    __hip_bfloat16* ctx = vTp + hsz;
    unsigned long long* bits = (unsigned long long*)(ctx + hsz);       // 1 MB
    float* linvb = (float*)(bits + (size_t)BB * SS * (SS / 64));       // 256 KB
    short* wtq = (short*)(linvb + (size_t)BB * HH * SS);               // 4 x 2 MB
    short* wtk = wtq + (size_t)DD * DD;
    short* wtv = wtk + (size_t)DD * DD;
    short* wto = wtv + (size_t)DD * DD;
    short* qb  = wto + (size_t)DD * DD;                                // 3 x 8 MB
    short* kb2 = qb  + (size_t)BB * SS * DD;
    short* vb2 = kb2 + (size_t)BB * SS * DD;

    dim3 gw(16, 16, 7);   // z=0..3 wT; z=4..6 q/k/v -> bf16
    wtrans_kernel<<<gw, 256, 0, stream>>>(wq, wk, wv, wo, q, k, v,
                                          wtq, wtk, wtv, wto, qb, kb2, vb2);

    dim3 gg(32, 8, 4);    // z=0: mask pack; z=1..3: q/k/v projections
    proj3_kernel<<<gg, 256, 0, stream>>>(qb, kb2, vb2, wtq, wtk, wtv, bq, bk, bv,
                                         qhp, khp, vTp, mask, bits);
    attn_compute_kernel<<<BB * HH * 16, 512, 0, stream>>>(qhp, khp, vTp, bits, linvb, ctx);

    dim3 gm(32, 8, 17);   // z=0: outproj; z=1..16: attn store slices
    outstore_kernel<<<gm, 256, 0, stream>>>(ctx, wto, bo, q, out,
                                            qhp, khp, bits, linvb, attn);
    ln_kernel<<<BB * SS, 256, 0, stream>>>(out, gamma, beta);
}

// Round 14
// 328.749 us; speedup vs baseline: 1.2271x; 1.0643x over previous
//
#include <hip/hip_runtime.h>
#include <hip/hip_bf16.h>

#define BB 2
#define SS 2048
#define DD 1024
#define HH 16
#define DKV 64

typedef __attribute__((ext_vector_type(8))) short short8;
typedef __attribute__((ext_vector_type(4))) short short4_t;
typedef __attribute__((ext_vector_type(4))) float f32x4;

#define MFMA16(a, b, c) __builtin_amdgcn_mfma_f32_16x16x32_bf16(a, b, c, 0, 0, 0)

__device__ __forceinline__ short f2bf(float f) {
    __hip_bfloat16 h = __float2bfloat16(f);
    union { __hip_bfloat16 h; short s; } u;
    u.h = h;
    return u.s;
}

// ---------------------------------------------------------------------------
// z=0..3: W[k][n] fp32 -> WT[n][k] bf16.  z=4..6: q/k/v fp32 -> bf16 copy.
// ---------------------------------------------------------------------------
__global__ __launch_bounds__(256) void wtrans_kernel(
    const float* __restrict__ w0, const float* __restrict__ w1,
    const float* __restrict__ w2, const float* __restrict__ w3,
    const float* __restrict__ qf, const float* __restrict__ kf, const float* __restrict__ vf,
    short* __restrict__ o0, short* __restrict__ o1,
    short* __restrict__ o2, short* __restrict__ o3,
    short* __restrict__ oq, short* __restrict__ ok, short* __restrict__ ov)
{
    const int z = blockIdx.z;
    const int t = threadIdx.x;
    if (z >= 4) {
        const float* src = (z == 4) ? qf : (z == 5) ? kf : vf;
        short* dst = (z == 4) ? oq : (z == 5) ? ok : ov;
        size_t idx = ((size_t)(blockIdx.y * 16 + blockIdx.x) * 256 + t) * 8;
        #pragma unroll
        for (int it = 0; it < 8; ++it, idx += 524288) {
            float4 a = *(const float4*)(src + idx);
            float4 b = *(const float4*)(src + idx + 4);
            short8 p = { f2bf(a.x), f2bf(a.y), f2bf(a.z), f2bf(a.w),
                         f2bf(b.x), f2bf(b.y), f2bf(b.z), f2bf(b.w) };
            *(short8*)(dst + idx) = p;
        }
        return;
    }
    const float* W = (z == 0) ? w0 : (z == 1) ? w1 : (z == 2) ? w2 : w3;
    short* O = (z == 0) ? o0 : (z == 1) ? o1 : (z == 2) ? o2 : o3;
    __shared__ short T[64][72];
    const int k0 = blockIdx.x * 64, n0 = blockIdx.y * 64;
    const int row = t >> 2, c = (t & 3) * 16;
    const float* src = W + (size_t)(k0 + row) * DD + n0 + c;
    #pragma unroll
    for (int i = 0; i < 16; i += 4) {
        float4 f = *(const float4*)(src + i);
        T[c + i + 0][row] = f2bf(f.x);
        T[c + i + 1][row] = f2bf(f.y);
        T[c + i + 2][row] = f2bf(f.z);
        T[c + i + 3][row] = f2bf(f.w);
    }
    __syncthreads();
    const int nr = t >> 2, kc = (t & 3) * 16;
    *(short8*)(O + (size_t)(n0 + nr) * DD + k0 + kc)     = *(const short8*)&T[nr][kc];
    *(short8*)(O + (size_t)(n0 + nr) * DD + k0 + kc + 8) = *(const short8*)&T[nr][kc + 8];
}

// ---------------------------------------------------------------------------
// Fused projection GEMMs + mask pack. A and B both pre-converted bf16.
// z=0: mask bit-pack; z=1,2 -> q,k [b][h][s][64]; z=3 -> vT[b][h][d][s].
// ---------------------------------------------------------------------------
__global__ __launch_bounds__(256) void proj3_kernel(
    const short* __restrict__ A0, const short* __restrict__ A1, const short* __restrict__ A2,
    const short* __restrict__ WT0, const short* __restrict__ WT1, const short* __restrict__ WT2,
    const float* __restrict__ bq, const float* __restrict__ bk, const float* __restrict__ bv,
    __hip_bfloat16* __restrict__ o0, __hip_bfloat16* __restrict__ o1, __hip_bfloat16* __restrict__ o2,
    const int* __restrict__ mask, unsigned long long* __restrict__ bits)
{
    const int t = threadIdx.x;
    const int lane = t & 63;
    const int wave = t >> 6;

    if (blockIdx.z == 0) {
        const int bid = blockIdx.y * 32 + blockIdx.x;
        const int base = bid * 512 + wave * 128;
        #pragma unroll 4
        for (int wi = base; wi < base + 128; ++wi) {
            const int mv = mask[(size_t)wi * 64 + lane];
            const unsigned long long bal = __ballot(mv != 0);
            if (lane == 0) bits[wi] = bal;
        }
        return;
    }

    const int z = blockIdx.z - 1;
    const short* A  = (z == 0) ? A0 : (z == 1) ? A1 : A2;
    const short* WT = (z == 0) ? WT0 : (z == 1) ? WT1 : WT2;
    const float* bias = (z == 0) ? bq : (z == 1) ? bk : bv;
    __hip_bfloat16* outh = (z == 0) ? o0 : (z == 1) ? o1 : o2;

    __shared__ __align__(16) short As[128][40];
    __shared__ __align__(16) short Bs[128][40];  // Bs[col][k]
    const int wm = wave >> 1, wn = wave & 1;
    const int m0 = blockIdx.x * 128, n0 = blockIdx.y * 128;
    const int lr = lane & 15;
    const int kb = (lane >> 4) * 8;
    const int row2 = t >> 1, kk2 = (t & 1) * 16;

    f32x4 acc[4][4] = {};

    for (int k0 = 0; k0 < DD; k0 += 32) {
        __syncthreads();
        {
            const short8* srca = (const short8*)(A + (size_t)(m0 + row2) * DD + k0 + kk2);
            *(short8*)&As[row2][kk2]     = srca[0];
            *(short8*)&As[row2][kk2 + 8] = srca[1];
        }
        {
            const short8* srcw = (const short8*)(WT + (size_t)(n0 + row2) * DD + k0 + kk2);
            *(short8*)&Bs[row2][kk2]     = srcw[0];
            *(short8*)&Bs[row2][kk2 + 8] = srcw[1];
        }
        __syncthreads();
        short8 af[4], bfr[4];
        #pragma unroll
        for (int i = 0; i < 4; i++) af[i]  = *(const short8*)&As[wm * 64 + i * 16 + lr][kb];
        #pragma unroll
        for (int j = 0; j < 4; j++) bfr[j] = *(const short8*)&Bs[wn * 64 + j * 16 + lr][kb];
        #pragma unroll
        for (int i = 0; i < 4; i++)
            #pragma unroll
            for (int j = 0; j < 4; j++)
                acc[i][j] = MFMA16(af[i], bfr[j], acc[i][j]);
    }

    if (z != 2) {
        #pragma unroll
        for (int j = 0; j < 4; j++) {
            const int col = n0 + wn * 64 + j * 16 + lr;
            const float bvv = bias[col];
            const int h = col >> 6, d = col & 63;
            #pragma unroll
            for (int i = 0; i < 4; i++) {
                #pragma unroll
                for (int r = 0; r < 4; r++) {
                    const int m = m0 + wm * 64 + i * 16 + (lane >> 4) * 4 + r;
                    const int b = m >> 11, s = m & (SS - 1);
                    outh[(((size_t)(b * HH + h)) * SS + s) * DKV + d] =
                        __float2bfloat16(acc[i][j][r] + bvv);
                }
            }
        }
    } else {
        short* vT = (short*)outh;
        #pragma unroll
        for (int j = 0; j < 4; j++) {
            const int col = n0 + wn * 64 + j * 16 + lr;
            const float bvv = bias[col];
            const int h = col >> 6, d = col & 63;
            #pragma unroll
            for (int i = 0; i < 4; i++) {
                const int m = m0 + wm * 64 + i * 16 + (lane >> 4) * 4;
                const int b = m >> 11, s = m & (SS - 1);
                short4_t pk;
                #pragma unroll
                for (int r = 0; r < 4; r++) pk[r] = f2bf(acc[i][j][r] + bvv);
                *(short4_t*)(vT + ((size_t)(b * HH + h) * DKV + d) * SS + s) = pk;
            }
        }
    }
}

// ---------------------------------------------------------------------------
// Attention kernel A (compute): QK + exp(unnorm) + row-sums + PV.
// (R10 structure: single-depth register prefetch, dbuf LDS.)
// ---------------------------------------------------------------------------
__global__ __launch_bounds__(512) void attn_compute_kernel(
    const __hip_bfloat16* __restrict__ qh, const __hip_bfloat16* __restrict__ kh,
    const __hip_bfloat16* __restrict__ vT, const unsigned long long* __restrict__ bits,
    float* __restrict__ linvb, __hip_bfloat16* __restrict__ ctx)
{
    __shared__ __align__(16) short Ks[2][64][72];
    __shared__ __align__(16) short Vs[2][64][72];
    __shared__ __align__(16) short Ps[8][16][72];
    const int t = threadIdx.x, lane = t & 63, w = t >> 6;

    const int logical = (blockIdx.x & 7) * 64 + (blockIdx.x >> 3);
    const int qt = logical & 15;
    const int bh = logical >> 4;
    const int h = bh & (HH - 1);
    const int b = bh >> 4;
    const int q0w = qt * 128 + w * 16;
    const size_t headbase = (size_t)bh * SS * DKV;
    const int lr = lane & 15;
    const int kb = (lane >> 4) * 8;
    const int rbase = (lane >> 4) * 4;

    const short* kbase = (const short*)kh + headbase;
    const short* vbase = (const short*)vT + (size_t)bh * DKV * SS;
    const unsigned long long* bitrow = bits + ((size_t)b * SS + q0w) * (SS / 64);

    const int srow = t >> 3, sc8 = (t & 7) * 8;
    const short* kstg = kbase + (size_t)srow * DKV + sc8;
    const short* vstg = vbase + (size_t)srow * SS + sc8;

    const short* qrp = (const short*)qh + headbase + (size_t)(q0w + lr) * DKV;
    const short8 aq0 = *(const short8*)(qrp + kb);
    const short8 aq1 = *(const short8*)(qrp + 32 + kb);

    float lsum[4] = {0.f, 0.f, 0.f, 0.f};
    f32x4 cacc[4] = {};

    {
        short8 kreg = *(const short8*)(kstg);
        short8 vreg = *(const short8*)(vstg);
        *(short8*)&Ks[0][srow][sc8] = kreg;
        *(short8*)&Vs[0][srow][sc8] = vreg;
        __syncthreads();
        for (int kt = 0; kt < 32; ++kt) {
            const int cur = kt & 1;
            if (kt + 1 < 32) {
                kreg = *(const short8*)(kstg + (size_t)(kt + 1) * 64 * DKV);
                vreg = *(const short8*)(vstg + (size_t)(kt + 1) * 64);
            }
            f32x4 sc[4];
            __builtin_amdgcn_s_setprio(1);
            #pragma unroll
            for (int fc = 0; fc < 4; ++fc) {
                short8 bk0 = *(const short8*)&Ks[cur][fc * 16 + lr][kb];
                short8 bk1 = *(const short8*)&Ks[cur][fc * 16 + lr][32 + kb];
                f32x4 s = {0.f, 0.f, 0.f, 0.f};
                s = MFMA16(aq0, bk0, s);
                s = MFMA16(aq1, bk1, s);
                sc[fc] = s;
            }
            __builtin_amdgcn_s_setprio(0);
            unsigned long long mw[4];
            #pragma unroll
            for (int r = 0; r < 4; ++r)
                mw[r] = bitrow[(size_t)(rbase + r) * (SS / 64) + kt];
            #pragma unroll
            for (int fc = 0; fc < 4; ++fc)
                #pragma unroll
                for (int r = 0; r < 4; ++r) {
                    const bool masked = (mw[r] >> (fc * 16 + lr)) & 1ull;
                    const float p = masked ? 0.f : __expf(sc[fc][r] * 0.125f);
                    lsum[r] += p;
                    Ps[w][rbase + r][fc * 16 + lr] = f2bf(p);
                }
            short8 ap0 = *(const short8*)&Ps[w][lr][kb];
            short8 ap1 = *(const short8*)&Ps[w][lr][32 + kb];
            __builtin_amdgcn_s_setprio(1);
            #pragma unroll
            for (int fd = 0; fd < 4; ++fd) {
                short8 bv0 = *(const short8*)&Vs[cur][fd * 16 + lr][kb];
                short8 bv1 = *(const short8*)&Vs[cur][fd * 16 + lr][32 + kb];
                cacc[fd] = MFMA16(ap0, bv0, cacc[fd]);
                cacc[fd] = MFMA16(ap1, bv1, cacc[fd]);
            }
            __builtin_amdgcn_s_setprio(0);
            if (kt + 1 < 32) {
                *(short8*)&Ks[cur ^ 1][srow][sc8] = kreg;
                *(short8*)&Vs[cur ^ 1][srow][sc8] = vreg;
            }
            __syncthreads();
        }
    }
    #pragma unroll
    for (int r = 0; r < 4; r++) {
        float s = lsum[r];
        s += __shfl_xor(s, 1);
        s += __shfl_xor(s, 2);
        s += __shfl_xor(s, 4);
        s += __shfl_xor(s, 8);
        lsum[r] = s;
    }
    float linv[4];
    #pragma unroll
    for (int r = 0; r < 4; r++) linv[r] = 1.f / lsum[r];

    if (lr == 0) {
        #pragma unroll
        for (int r = 0; r < 4; r++)
            linvb[(size_t)bh * SS + q0w + rbase + r] = linv[r];
    }

    #pragma unroll
    for (int fd = 0; fd < 4; ++fd)
        #pragma unroll
        for (int r = 0; r < 4; r++) {
            const int qrow = q0w + rbase + r;
            ctx[((size_t)b * SS + qrow) * DD + h * DKV + fd * 16 + lr] =
                __float2bfloat16(cacc[fd][r] * linv[r]);
        }
}

// ---------------------------------------------------------------------------
// Merged kernel: z=0 -> output GEMM (+bias+residual); z=1..32 -> attn store
// slices (64q x 256k each; 36KB LDS -> 4 blocks/CU for the write drain).
// ---------------------------------------------------------------------------
__global__ __launch_bounds__(256) void outstore_kernel(
    const __hip_bfloat16* __restrict__ Actx, const short* __restrict__ WT,
    const float* __restrict__ bias, const float* __restrict__ resid,
    float* __restrict__ out,
    const __hip_bfloat16* __restrict__ qh, const __hip_bfloat16* __restrict__ kh,
    const unsigned long long* __restrict__ bits, const float* __restrict__ linvb,
    float* __restrict__ attn)
{
    __shared__ __align__(16) short LDSBUF[18432];   // 36KB, unioned
    const int t = threadIdx.x, lane = t & 63, w = t >> 6;
    const int lr = lane & 15;
    const int kb = (lane >> 4) * 8;

    if (blockIdx.z == 0) {
        // ---------------- output GEMM ----------------
        short (*As)[40] = (short(*)[40])LDSBUF;
        short (*Bs)[40] = (short(*)[40])(LDSBUF + 5120);
        const int wave = w;
        const int wm = wave >> 1, wn = wave & 1;
        const int m0 = blockIdx.x * 128, n0 = blockIdx.y * 128;
        const int row2 = t >> 1, kk2 = (t & 1) * 16;

        f32x4 acc[4][4] = {};

        for (int k0 = 0; k0 < DD; k0 += 32) {
            __syncthreads();
            {
                const short8* src = (const short8*)((const short*)Actx + (size_t)(m0 + row2) * DD + k0 + kk2);
                *(short8*)&As[row2][kk2]     = src[0];
                *(short8*)&As[row2][kk2 + 8] = src[1];
            }
            {
                const short8* srcw = (const short8*)(WT + (size_t)(n0 + row2) * DD + k0 + kk2);
                *(short8*)&Bs[row2][kk2]     = srcw[0];
                *(short8*)&Bs[row2][kk2 + 8] = srcw[1];
            }
            __syncthreads();
            short8 af[4], bfr[4];
            #pragma unroll
            for (int i = 0; i < 4; i++) af[i]  = *(const short8*)&As[wm * 64 + i * 16 + lr][kb];
            #pragma unroll
            for (int j = 0; j < 4; j++) bfr[j] = *(const short8*)&Bs[wn * 64 + j * 16 + lr][kb];
            #pragma unroll
            for (int i = 0; i < 4; i++)
                #pragma unroll
                for (int j = 0; j < 4; j++)
                    acc[i][j] = MFMA16(af[i], bfr[j], acc[i][j]);
        }

        #pragma unroll
        for (int j = 0; j < 4; j++) {
            const int col = n0 + wn * 64 + j * 16 + lr;
            const float bvv = bias[col];
            #pragma unroll
            for (int i = 0; i < 4; i++) {
                #pragma unroll
                for (int r = 0; r < 4; r++) {
                    const int m = m0 + wm * 64 + i * 16 + (lane >> 4) * 4 + r;
                    out[(size_t)m * DD + col] = acc[i][j][r] + bvv + resid[(size_t)m * DD + col];
                }
            }
        }
        return;
    }

    // ---------------- attn store slice: 64q x 256k ----------------
    short (*Ks)[72] = (short(*)[72])LDSBUF;         // 256 x 72
    const int sb = (blockIdx.z - 1) * 256 + blockIdx.y * 32 + blockIdx.x;  // 0..8191
    const int qt = sb & 31;
    const int kc = (sb >> 5) & 7;
    const int bh = sb >> 8;
    const int b = bh >> 4;
    const int q0w = qt * 64 + w * 16;
    const int k0c = kc * 256;
    const size_t headbase = (size_t)bh * SS * DKV;
    const int Q4 = lane >> 4;
    const int rbase = Q4 * 4;

    {
        const short* kbase = (const short*)kh + headbase + (size_t)k0c * DKV;
        const int c8 = (t & 7) * 8;
        #pragma unroll
        for (int sweep = 0; sweep < 8; ++sweep) {
            const int row = (t >> 3) + sweep * 32;
            *(short8*)&Ks[row][c8] = *(const short8*)(kbase + (size_t)row * DKV + c8);
        }
    }

    const short* qrp = (const short*)qh + headbase + (size_t)(q0w + lr) * DKV;
    const short8 aq0 = *(const short8*)(qrp + kb);
    const short8 aq1 = *(const short8*)(qrp + 32 + kb);

    float linv[4];
    #pragma unroll
    for (int r = 0; r < 4; ++r)
        linv[r] = linvb[(size_t)bh * SS + q0w + rbase + r];

    const unsigned long long* bitrow = bits + ((size_t)b * SS + q0w) * (SS / 64);
    float* arow = attn + ((size_t)bh * SS + q0w) * SS + k0c;

    __syncthreads();

    for (int g = 0; g < 4; ++g) {
        unsigned long long mw[4];
        #pragma unroll
        for (int r = 0; r < 4; ++r)
            mw[r] = bitrow[(size_t)(rbase + r) * (SS / 64) + kc * 4 + g];
        #pragma unroll
        for (int fc = 0; fc < 4; ++fc) {
            const int col = g * 64 + fc * 16;
            short8 bk0 = *(const short8*)&Ks[col + lr][kb];
            short8 bk1 = *(const short8*)&Ks[col + lr][32 + kb];
            f32x4 s = {0.f, 0.f, 0.f, 0.f};
            s = MFMA16(aq0, bk0, s);
            s = MFMA16(aq1, bk1, s);
            #pragma unroll
            for (int r = 0; r < 4; ++r) {
                const bool masked = (mw[r] >> (fc * 16 + lr)) & 1ull;
                const float p = masked ? 0.f : __expf(s[r] * 0.125f) * linv[r];
                arow[(size_t)(rbase + r) * SS + col + lr] = p;
            }
        }
    }
}

// ---------------------------------------------------------------------------
// LayerNorm in place on out[4096][1024], biased var, eps=1e-5
// ---------------------------------------------------------------------------
__global__ __launch_bounds__(256) void ln_kernel(
    float* __restrict__ io, const float* __restrict__ g, const float* __restrict__ bta)
{
    const int row = blockIdx.x;
    const int t = threadIdx.x;
    float* p = io + (size_t)row * DD;
    float4 x = *(float4*)(p + t * 4);
    float s  = x.x + x.y + x.z + x.w;
    float s2 = x.x * x.x + x.y * x.y + x.z * x.z + x.w * x.w;
    #pragma unroll
    for (int off = 32; off; off >>= 1) {
        s  += __shfl_xor(s, off);
        s2 += __shfl_xor(s2, off);
    }
    __shared__ float as_[4], bs_[4];
    const int w = t >> 6, l = t & 63;
    if (!l) { as_[w] = s; bs_[w] = s2; }
    __syncthreads();
    s  = as_[0] + as_[1] + as_[2] + as_[3];
    s2 = bs_[0] + bs_[1] + bs_[2] + bs_[3];
    const float mu  = s * (1.f / DD);
    const float var = s2 * (1.f / DD) - mu * mu;
    const float rs  = rsqrtf(var + 1e-5f);
    float4 gv = *(const float4*)(g + t * 4);
    float4 bv = *(const float4*)(bta + t * 4);
    float4 o;
    o.x = (x.x - mu) * rs * gv.x + bv.x;
    o.y = (x.y - mu) * rs * gv.y + bv.y;
    o.z = (x.z - mu) * rs * gv.z + bv.z;
    o.w = (x.w - mu) * rs * gv.w + bv.w;
    *(float4*)(p + t * 4) = o;
}

// ---------------------------------------------------------------------------
extern "C" void kernel_launch(void* const* d_in, const int* in_sizes, int n_in,
                              void* d_out, int out_size, void* d_ws, size_t ws_size,
                              hipStream_t stream)
{
    (void)in_sizes; (void)n_in; (void)out_size; (void)ws_size;
    const float* q     = (const float*)d_in[0];
    const float* k     = (const float*)d_in[1];
    const float* v     = (const float*)d_in[2];
    const int*   mask  = (const int*)d_in[3];
    const float* wq    = (const float*)d_in[4];
    const float* bq    = (const float*)d_in[5];
    const float* wk    = (const float*)d_in[6];
    const float* bk    = (const float*)d_in[7];
    const float* wv    = (const float*)d_in[8];
    const float* bv    = (const float*)d_in[9];
    const float* wo    = (const float*)d_in[10];
    const float* bo    = (const float*)d_in[11];
    const float* gamma = (const float*)d_in[12];
    const float* beta  = (const float*)d_in[13];

    float* out  = (float*)d_out;                    // [B,S,D]
    float* attn = out + (size_t)BB * SS * DD;       // [B,H,S,S]

    const size_t hsz = (size_t)BB * HH * SS * DKV;  // 4,194,304
    __hip_bfloat16* qhp = (__hip_bfloat16*)d_ws;
    __hip_bfloat16* khp = qhp + hsz;
    __hip_bfloat16* vTp = khp + hsz;                // vT[b][h][d][s]
    __hip_bfloat16* ctx = vTp + hsz;
    unsigned long long* bits = (unsigned long long*)(ctx + hsz);       // 1 MB
    float* linvb = (float*)(bits + (size_t)BB * SS * (SS / 64));       // 256 KB
    short* wtq = (short*)(linvb + (size_t)BB * HH * SS);               // 4 x 2 MB
    short* wtk = wtq + (size_t)DD * DD;
    short* wtv = wtk + (size_t)DD * DD;
    short* wto = wtv + (size_t)DD * DD;
    short* qb  = wto + (size_t)DD * DD;                                // 3 x 8 MB
    short* kb2 = qb  + (size_t)BB * SS * DD;
    short* vb2 = kb2 + (size_t)BB * SS * DD;

    dim3 gw(16, 16, 7);   // z=0..3 wT; z=4..6 q/k/v -> bf16
    wtrans_kernel<<<gw, 256, 0, stream>>>(wq, wk, wv, wo, q, k, v,
                                          wtq, wtk, wtv, wto, qb, kb2, vb2);

    dim3 gg(32, 8, 4);    // z=0: mask pack; z=1..3: q/k/v projections
    proj3_kernel<<<gg, 256, 0, stream>>>(qb, kb2, vb2, wtq, wtk, wtv, bq, bk, bv,
                                         qhp, khp, vTp, mask, bits);
    attn_compute_kernel<<<BB * HH * 16, 512, 0, stream>>>(qhp, khp, vTp, bits, linvb, ctx);

    dim3 gm(32, 8, 33);   // z=0: outproj; z=1..32: attn store slices (8192)
    outstore_kernel<<<gm, 256, 0, stream>>>(ctx, wto, bo, q, out,
                                            qhp, khp, bits, linvb, attn);
    ln_kernel<<<BB * SS, 256, 0, stream>>>(out, gamma, beta);
}

// Round 15
// 317.351 us; speedup vs baseline: 1.2712x; 1.0359x over previous
//
#include <hip/hip_runtime.h>
#include <hip/hip_bf16.h>

#define BB 2
#define SS 2048
#define DD 1024
#define HH 16
#define DKV 64

typedef __attribute__((ext_vector_type(8))) short short8;
typedef __attribute__((ext_vector_type(4))) short short4_t;
typedef __attribute__((ext_vector_type(4))) float f32x4;

#define MFMA16(a, b, c) __builtin_amdgcn_mfma_f32_16x16x32_bf16(a, b, c, 0, 0, 0)

__device__ __forceinline__ short f2bf(float f) {
    __hip_bfloat16 h = __float2bfloat16(f);
    union { __hip_bfloat16 h; short s; } u;
    u.h = h;
    return u.s;
}

// ---------------------------------------------------------------------------
// z=0..3: W[k][n] fp32 -> WT[n][k] bf16.  z=4..6: q/k/v fp32 -> bf16 copy.
// ---------------------------------------------------------------------------
__global__ __launch_bounds__(256) void wtrans_kernel(
    const float* __restrict__ w0, const float* __restrict__ w1,
    const float* __restrict__ w2, const float* __restrict__ w3,
    const float* __restrict__ qf, const float* __restrict__ kf, const float* __restrict__ vf,
    short* __restrict__ o0, short* __restrict__ o1,
    short* __restrict__ o2, short* __restrict__ o3,
    short* __restrict__ oq, short* __restrict__ ok, short* __restrict__ ov)
{
    const int z = blockIdx.z;
    const int t = threadIdx.x;
    if (z >= 4) {
        const float* src = (z == 4) ? qf : (z == 5) ? kf : vf;
        short* dst = (z == 4) ? oq : (z == 5) ? ok : ov;
        size_t idx = ((size_t)(blockIdx.y * 16 + blockIdx.x) * 256 + t) * 8;
        #pragma unroll
        for (int it = 0; it < 8; ++it, idx += 524288) {
            float4 a = *(const float4*)(src + idx);
            float4 b = *(const float4*)(src + idx + 4);
            short8 p = { f2bf(a.x), f2bf(a.y), f2bf(a.z), f2bf(a.w),
                         f2bf(b.x), f2bf(b.y), f2bf(b.z), f2bf(b.w) };
            *(short8*)(dst + idx) = p;
        }
        return;
    }
    const float* W = (z == 0) ? w0 : (z == 1) ? w1 : (z == 2) ? w2 : w3;
    short* O = (z == 0) ? o0 : (z == 1) ? o1 : (z == 2) ? o2 : o3;
    __shared__ short T[64][72];
    const int k0 = blockIdx.x * 64, n0 = blockIdx.y * 64;
    const int row = t >> 2, c = (t & 3) * 16;
    const float* src = W + (size_t)(k0 + row) * DD + n0 + c;
    #pragma unroll
    for (int i = 0; i < 16; i += 4) {
        float4 f = *(const float4*)(src + i);
        T[c + i + 0][row] = f2bf(f.x);
        T[c + i + 1][row] = f2bf(f.y);
        T[c + i + 2][row] = f2bf(f.z);
        T[c + i + 3][row] = f2bf(f.w);
    }
    __syncthreads();
    const int nr = t >> 2, kc = (t & 3) * 16;
    *(short8*)(O + (size_t)(n0 + nr) * DD + k0 + kc)     = *(const short8*)&T[nr][kc];
    *(short8*)(O + (size_t)(n0 + nr) * DD + k0 + kc + 8) = *(const short8*)&T[nr][kc + 8];
}

// ---------------------------------------------------------------------------
// Fused projection GEMMs + mask pack. BK=64 (16 iters, 32 MFMA/iter).
// z=0: mask bit-pack; z=1,2 -> q,k [b][h][s][64]; z=3 -> vT[b][h][d][s].
// ---------------------------------------------------------------------------
__global__ __launch_bounds__(256) void proj3_kernel(
    const short* __restrict__ A0, const short* __restrict__ A1, const short* __restrict__ A2,
    const short* __restrict__ WT0, const short* __restrict__ WT1, const short* __restrict__ WT2,
    const float* __restrict__ bq, const float* __restrict__ bk, const float* __restrict__ bv,
    __hip_bfloat16* __restrict__ o0, __hip_bfloat16* __restrict__ o1, __hip_bfloat16* __restrict__ o2,
    const int* __restrict__ mask, unsigned long long* __restrict__ bits)
{
    const int t = threadIdx.x;
    const int lane = t & 63;
    const int wave = t >> 6;

    if (blockIdx.z == 0) {
        const int bid = blockIdx.y * 32 + blockIdx.x;
        const int base = bid * 512 + wave * 128;
        #pragma unroll 4
        for (int wi = base; wi < base + 128; ++wi) {
            const int mv = mask[(size_t)wi * 64 + lane];
            const unsigned long long bal = __ballot(mv != 0);
            if (lane == 0) bits[wi] = bal;
        }
        return;
    }

    const int z = blockIdx.z - 1;
    const short* A  = (z == 0) ? A0 : (z == 1) ? A1 : A2;
    const short* WT = (z == 0) ? WT0 : (z == 1) ? WT1 : WT2;
    const float* bias = (z == 0) ? bq : (z == 1) ? bk : bv;
    __hip_bfloat16* outh = (z == 0) ? o0 : (z == 1) ? o1 : o2;

    __shared__ __align__(16) short As[128][72];
    __shared__ __align__(16) short Bs[128][72];  // Bs[col][k]
    const int wm = wave >> 1, wn = wave & 1;
    const int m0 = blockIdx.x * 128, n0 = blockIdx.y * 128;
    const int lr = lane & 15;
    const int kb = (lane >> 4) * 8;
    const int row2 = t >> 1, kk2 = (t & 1) * 32;

    f32x4 acc[4][4] = {};

    for (int k0 = 0; k0 < DD; k0 += 64) {
        __syncthreads();
        {
            const short8* srca = (const short8*)(A + (size_t)(m0 + row2) * DD + k0 + kk2);
            *(short8*)&As[row2][kk2]      = srca[0];
            *(short8*)&As[row2][kk2 + 8]  = srca[1];
            *(short8*)&As[row2][kk2 + 16] = srca[2];
            *(short8*)&As[row2][kk2 + 24] = srca[3];
        }
        {
            const short8* srcw = (const short8*)(WT + (size_t)(n0 + row2) * DD + k0 + kk2);
            *(short8*)&Bs[row2][kk2]      = srcw[0];
            *(short8*)&Bs[row2][kk2 + 8]  = srcw[1];
            *(short8*)&Bs[row2][kk2 + 16] = srcw[2];
            *(short8*)&Bs[row2][kk2 + 24] = srcw[3];
        }
        __syncthreads();
        #pragma unroll
        for (int half = 0; half < 2; ++half) {
            const int ko = half * 32 + kb;
            short8 af[4], bfr[4];
            #pragma unroll
            for (int i = 0; i < 4; i++) af[i]  = *(const short8*)&As[wm * 64 + i * 16 + lr][ko];
            #pragma unroll
            for (int j = 0; j < 4; j++) bfr[j] = *(const short8*)&Bs[wn * 64 + j * 16 + lr][ko];
            #pragma unroll
            for (int i = 0; i < 4; i++)
                #pragma unroll
                for (int j = 0; j < 4; j++)
                    acc[i][j] = MFMA16(af[i], bfr[j], acc[i][j]);
        }
    }

    if (z != 2) {
        #pragma unroll
        for (int j = 0; j < 4; j++) {
            const int col = n0 + wn * 64 + j * 16 + lr;
            const float bvv = bias[col];
            const int h = col >> 6, d = col & 63;
            #pragma unroll
            for (int i = 0; i < 4; i++) {
                #pragma unroll
                for (int r = 0; r < 4; r++) {
                    const int m = m0 + wm * 64 + i * 16 + (lane >> 4) * 4 + r;
                    const int b = m >> 11, s = m & (SS - 1);
                    outh[(((size_t)(b * HH + h)) * SS + s) * DKV + d] =
                        __float2bfloat16(acc[i][j][r] + bvv);
                }
            }
        }
    } else {
        short* vT = (short*)outh;
        #pragma unroll
        for (int j = 0; j < 4; j++) {
            const int col = n0 + wn * 64 + j * 16 + lr;
            const float bvv = bias[col];
            const int h = col >> 6, d = col & 63;
            #pragma unroll
            for (int i = 0; i < 4; i++) {
                const int m = m0 + wm * 64 + i * 16 + (lane >> 4) * 4;
                const int b = m >> 11, s = m & (SS - 1);
                short4_t pk;
                #pragma unroll
                for (int r = 0; r < 4; r++) pk[r] = f2bf(acc[i][j][r] + bvv);
                *(short4_t*)(vT + ((size_t)(b * HH + h) * DKV + d) * SS + s) = pk;
            }
        }
    }
}

// ---------------------------------------------------------------------------
// Attention kernel A (compute): QK + exp(unnorm) + row-sums + PV.
// (R10/R14 structure: single-depth register prefetch, dbuf LDS.)
// ---------------------------------------------------------------------------
__global__ __launch_bounds__(512) void attn_compute_kernel(
    const __hip_bfloat16* __restrict__ qh, const __hip_bfloat16* __restrict__ kh,
    const __hip_bfloat16* __restrict__ vT, const unsigned long long* __restrict__ bits,
    float* __restrict__ linvb, __hip_bfloat16* __restrict__ ctx)
{
    __shared__ __align__(16) short Ks[2][64][72];
    __shared__ __align__(16) short Vs[2][64][72];
    __shared__ __align__(16) short Ps[8][16][72];
    const int t = threadIdx.x, lane = t & 63, w = t >> 6;

    const int logical = (blockIdx.x & 7) * 64 + (blockIdx.x >> 3);
    const int qt = logical & 15;
    const int bh = logical >> 4;
    const int h = bh & (HH - 1);
    const int b = bh >> 4;
    const int q0w = qt * 128 + w * 16;
    const size_t headbase = (size_t)bh * SS * DKV;
    const int lr = lane & 15;
    const int kb = (lane >> 4) * 8;
    const int rbase = (lane >> 4) * 4;

    const short* kbase = (const short*)kh + headbase;
    const short* vbase = (const short*)vT + (size_t)bh * DKV * SS;
    const unsigned long long* bitrow = bits + ((size_t)b * SS + q0w) * (SS / 64);

    const int srow = t >> 3, sc8 = (t & 7) * 8;
    const short* kstg = kbase + (size_t)srow * DKV + sc8;
    const short* vstg = vbase + (size_t)srow * SS + sc8;

    const short* qrp = (const short*)qh + headbase + (size_t)(q0w + lr) * DKV;
    const short8 aq0 = *(const short8*)(qrp + kb);
    const short8 aq1 = *(const short8*)(qrp + 32 + kb);

    float lsum[4] = {0.f, 0.f, 0.f, 0.f};
    f32x4 cacc[4] = {};

    {
        short8 kreg = *(const short8*)(kstg);
        short8 vreg = *(const short8*)(vstg);
        *(short8*)&Ks[0][srow][sc8] = kreg;
        *(short8*)&Vs[0][srow][sc8] = vreg;
        __syncthreads();
        for (int kt = 0; kt < 32; ++kt) {
            const int cur = kt & 1;
            if (kt + 1 < 32) {
                kreg = *(const short8*)(kstg + (size_t)(kt + 1) * 64 * DKV);
                vreg = *(const short8*)(vstg + (size_t)(kt + 1) * 64);
            }
            f32x4 sc[4];
            __builtin_amdgcn_s_setprio(1);
            #pragma unroll
            for (int fc = 0; fc < 4; ++fc) {
                short8 bk0 = *(const short8*)&Ks[cur][fc * 16 + lr][kb];
                short8 bk1 = *(const short8*)&Ks[cur][fc * 16 + lr][32 + kb];
                f32x4 s = {0.f, 0.f, 0.f, 0.f};
                s = MFMA16(aq0, bk0, s);
                s = MFMA16(aq1, bk1, s);
                sc[fc] = s;
            }
            __builtin_amdgcn_s_setprio(0);
            unsigned long long mw[4];
            #pragma unroll
            for (int r = 0; r < 4; ++r)
                mw[r] = bitrow[(size_t)(rbase + r) * (SS / 64) + kt];
            #pragma unroll
            for (int fc = 0; fc < 4; ++fc)
                #pragma unroll
                for (int r = 0; r < 4; ++r) {
                    const bool masked = (mw[r] >> (fc * 16 + lr)) & 1ull;
                    const float p = masked ? 0.f : __expf(sc[fc][r] * 0.125f);
                    lsum[r] += p;
                    Ps[w][rbase + r][fc * 16 + lr] = f2bf(p);
                }
            short8 ap0 = *(const short8*)&Ps[w][lr][kb];
            short8 ap1 = *(const short8*)&Ps[w][lr][32 + kb];
            __builtin_amdgcn_s_setprio(1);
            #pragma unroll
            for (int fd = 0; fd < 4; ++fd) {
                short8 bv0 = *(const short8*)&Vs[cur][fd * 16 + lr][kb];
                short8 bv1 = *(const short8*)&Vs[cur][fd * 16 + lr][32 + kb];
                cacc[fd] = MFMA16(ap0, bv0, cacc[fd]);
                cacc[fd] = MFMA16(ap1, bv1, cacc[fd]);
            }
            __builtin_amdgcn_s_setprio(0);
            if (kt + 1 < 32) {
                *(short8*)&Ks[cur ^ 1][srow][sc8] = kreg;
                *(short8*)&Vs[cur ^ 1][srow][sc8] = vreg;
            }
            __syncthreads();
        }
    }
    #pragma unroll
    for (int r = 0; r < 4; r++) {
        float s = lsum[r];
        s += __shfl_xor(s, 1);
        s += __shfl_xor(s, 2);
        s += __shfl_xor(s, 4);
        s += __shfl_xor(s, 8);
        lsum[r] = s;
    }
    float linv[4];
    #pragma unroll
    for (int r = 0; r < 4; r++) linv[r] = 1.f / lsum[r];

    if (lr == 0) {
        #pragma unroll
        for (int r = 0; r < 4; r++)
            linvb[(size_t)bh * SS + q0w + rbase + r] = linv[r];
    }

    #pragma unroll
    for (int fd = 0; fd < 4; ++fd)
        #pragma unroll
        for (int r = 0; r < 4; r++) {
            const int qrow = q0w + rbase + r;
            ctx[((size_t)b * SS + qrow) * DD + h * DKV + fd * 16 + lr] =
                __float2bfloat16(cacc[fd][r] * linv[r]);
        }
}

// ---------------------------------------------------------------------------
// Merged kernel: z=0 -> output GEMM (BK=64); z=1..32 -> attn store slices
// (64q x 256k each; 36KB LDS).
// ---------------------------------------------------------------------------
__global__ __launch_bounds__(256) void outstore_kernel(
    const __hip_bfloat16* __restrict__ Actx, const short* __restrict__ WT,
    const float* __restrict__ bias, const float* __restrict__ resid,
    float* __restrict__ out,
    const __hip_bfloat16* __restrict__ qh, const __hip_bfloat16* __restrict__ kh,
    const unsigned long long* __restrict__ bits, const float* __restrict__ linvb,
    float* __restrict__ attn)
{
    __shared__ __align__(16) short LDSBUF[18432];   // 36KB, unioned
    const int t = threadIdx.x, lane = t & 63, w = t >> 6;
    const int lr = lane & 15;
    const int kb = (lane >> 4) * 8;

    if (blockIdx.z == 0) {
        // ---------------- output GEMM, BK=64 ----------------
        short (*As)[72] = (short(*)[72])LDSBUF;
        short (*Bs)[72] = (short(*)[72])(LDSBUF + 9216);
        const int wave = w;
        const int wm = wave >> 1, wn = wave & 1;
        const int m0 = blockIdx.x * 128, n0 = blockIdx.y * 128;
        const int row2 = t >> 1, kk2 = (t & 1) * 32;

        f32x4 acc[4][4] = {};

        for (int k0 = 0; k0 < DD; k0 += 64) {
            __syncthreads();
            {
                const short8* src = (const short8*)((const short*)Actx + (size_t)(m0 + row2) * DD + k0 + kk2);
                *(short8*)&As[row2][kk2]      = src[0];
                *(short8*)&As[row2][kk2 + 8]  = src[1];
                *(short8*)&As[row2][kk2 + 16] = src[2];
                *(short8*)&As[row2][kk2 + 24] = src[3];
            }
            {
                const short8* srcw = (const short8*)(WT + (size_t)(n0 + row2) * DD + k0 + kk2);
                *(short8*)&Bs[row2][kk2]      = srcw[0];
                *(short8*)&Bs[row2][kk2 + 8]  = srcw[1];
                *(short8*)&Bs[row2][kk2 + 16] = srcw[2];
                *(short8*)&Bs[row2][kk2 + 24] = srcw[3];
            }
            __syncthreads();
            #pragma unroll
            for (int half = 0; half < 2; ++half) {
                const int ko = half * 32 + kb;
                short8 af[4], bfr[4];
                #pragma unroll
                for (int i = 0; i < 4; i++) af[i]  = *(const short8*)&As[wm * 64 + i * 16 + lr][ko];
                #pragma unroll
                for (int j = 0; j < 4; j++) bfr[j] = *(const short8*)&Bs[wn * 64 + j * 16 + lr][ko];
                #pragma unroll
                for (int i = 0; i < 4; i++)
                    #pragma unroll
                    for (int j = 0; j < 4; j++)
                        acc[i][j] = MFMA16(af[i], bfr[j], acc[i][j]);
            }
        }

        #pragma unroll
        for (int j = 0; j < 4; j++) {
            const int col = n0 + wn * 64 + j * 16 + lr;
            const float bvv = bias[col];
            #pragma unroll
            for (int i = 0; i < 4; i++) {
                #pragma unroll
                for (int r = 0; r < 4; r++) {
                    const int m = m0 + wm * 64 + i * 16 + (lane >> 4) * 4 + r;
                    out[(size_t)m * DD + col] = acc[i][j][r] + bvv + resid[(size_t)m * DD + col];
                }
            }
        }
        return;
    }

    // ---------------- attn store slice: 64q x 256k ----------------
    short (*Ks)[72] = (short(*)[72])LDSBUF;         // 256 x 72
    const int sb = (blockIdx.z - 1) * 256 + blockIdx.y * 32 + blockIdx.x;  // 0..8191
    const int qt = sb & 31;
    const int kc = (sb >> 5) & 7;
    const int bh = sb >> 8;
    const int b = bh >> 4;
    const int q0w = qt * 64 + w * 16;
    const int k0c = kc * 256;
    const size_t headbase = (size_t)bh * SS * DKV;
    const int Q4 = lane >> 4;
    const int rbase = Q4 * 4;

    {
        const short* kbase = (const short*)kh + headbase + (size_t)k0c * DKV;
        const int c8 = (t & 7) * 8;
        #pragma unroll
        for (int sweep = 0; sweep < 8; ++sweep) {
            const int row = (t >> 3) + sweep * 32;
            *(short8*)&Ks[row][c8] = *(const short8*)(kbase + (size_t)row * DKV + c8);
        }
    }

    const short* qrp = (const short*)qh + headbase + (size_t)(q0w + lr) * DKV;
    const short8 aq0 = *(const short8*)(qrp + kb);
    const short8 aq1 = *(const short8*)(qrp + 32 + kb);

    float linv[4];
    #pragma unroll
    for (int r = 0; r < 4; ++r)
        linv[r] = linvb[(size_t)bh * SS + q0w + rbase + r];

    const unsigned long long* bitrow = bits + ((size_t)b * SS + q0w) * (SS / 64);
    float* arow = attn + ((size_t)bh * SS + q0w) * SS + k0c;

    __syncthreads();

    for (int g = 0; g < 4; ++g) {
        unsigned long long mw[4];
        #pragma unroll
        for (int r = 0; r < 4; ++r)
            mw[r] = bitrow[(size_t)(rbase + r) * (SS / 64) + kc * 4 + g];
        #pragma unroll
        for (int fc = 0; fc < 4; ++fc) {
            const int col = g * 64 + fc * 16;
            short8 bk0 = *(const short8*)&Ks[col + lr][kb];
            short8 bk1 = *(const short8*)&Ks[col + lr][32 + kb];
            f32x4 s = {0.f, 0.f, 0.f, 0.f};
            s = MFMA16(aq0, bk0, s);
            s = MFMA16(aq1, bk1, s);
            #pragma unroll
            for (int r = 0; r < 4; ++r) {
                const bool masked = (mw[r] >> (fc * 16 + lr)) & 1ull;
                const float p = masked ? 0.f : __expf(s[r] * 0.125f) * linv[r];
                arow[(size_t)(rbase + r) * SS + col + lr] = p;
            }
        }
    }
}

// ---------------------------------------------------------------------------
// LayerNorm in place on out[4096][1024], biased var, eps=1e-5
// ---------------------------------------------------------------------------
__global__ __launch_bounds__(256) void ln_kernel(
    float* __restrict__ io, const float* __restrict__ g, const float* __restrict__ bta)
{
    const int row = blockIdx.x;
    const int t = threadIdx.x;
    float* p = io + (size_t)row * DD;
    float4 x = *(float4*)(p + t * 4);
    float s  = x.x + x.y + x.z + x.w;
    float s2 = x.x * x.x + x.y * x.y + x.z * x.z + x.w * x.w;
    #pragma unroll
    for (int off = 32; off; off >>= 1) {
        s  += __shfl_xor(s, off);
        s2 += __shfl_xor(s2, off);
    }
    __shared__ float as_[4], bs_[4];
    const int w = t >> 6, l = t & 63;
    if (!l) { as_[w] = s; bs_[w] = s2; }
    __syncthreads();
    s  = as_[0] + as_[1] + as_[2] + as_[3];
    s2 = bs_[0] + bs_[1] + bs_[2] + bs_[3];
    const float mu  = s * (1.f / DD);
    const float var = s2 * (1.f / DD) - mu * mu;
    const float rs  = rsqrtf(var + 1e-5f);
    float4 gv = *(const float4*)(g + t * 4);
    float4 bv = *(const float4*)(bta + t * 4);
    float4 o;
    o.x = (x.x - mu) * rs * gv.x + bv.x;
    o.y = (x.y - mu) * rs * gv.y + bv.y;
    o.z = (x.z - mu) * rs * gv.z + bv.z;
    o.w = (x.w - mu) * rs * gv.w + bv.w;
    *(float4*)(p + t * 4) = o;
}

// ---------------------------------------------------------------------------
extern "C" void kernel_launch(void* const* d_in, const int* in_sizes, int n_in,
                              void* d_out, int out_size, void* d_ws, size_t ws_size,
                              hipStream_t stream)
{
    (void)in_sizes; (void)n_in; (void)out_size; (void)ws_size;
    const float* q     = (const float*)d_in[0];
    const float* k     = (const float*)d_in[1];
    const float* v     = (const float*)d_in[2];
    const int*   mask  = (const int*)d_in[3];
    const float* wq    = (const float*)d_in[4];
    const float* bq    = (const float*)d_in[5];
    const float* wk    = (const float*)d_in[6];
    const float* bk    = (const float*)d_in[7];
    const float* wv    = (const float*)d_in[8];
    const float* bv    = (const float*)d_in[9];
    const float* wo    = (const float*)d_in[10];
    const float* bo    = (const float*)d_in[11];
    const float* gamma = (const float*)d_in[12];
    const float* beta  = (const float*)d_in[13];

    float* out  = (float*)d_out;                    // [B,S,D]
    float* attn = out + (size_t)BB * SS * DD;       // [B,H,S,S]

    const size_t hsz = (size_t)BB * HH * SS * DKV;  // 4,194,304
    __hip_bfloat16* qhp = (__hip_bfloat16*)d_ws;
    __hip_bfloat16* khp = qhp + hsz;
    __hip_bfloat16* vTp = khp + hsz;                // vT[b][h][d][s]
    __hip_bfloat16* ctx = vTp + hsz;
    unsigned long long* bits = (unsigned long long*)(ctx + hsz);       // 1 MB
    float* linvb = (float*)(bits + (size_t)BB * SS * (SS / 64));       // 256 KB
    short* wtq = (short*)(linvb + (size_t)BB * HH * SS);               // 4 x 2 MB
    short* wtk = wtq + (size_t)DD * DD;
    short* wtv = wtk + (size_t)DD * DD;
    short* wto = wtv + (size_t)DD * DD;
    short* qb  = wto + (size_t)DD * DD;                                // 3 x 8 MB
    short* kb2 = qb  + (size_t)BB * SS * DD;
    short* vb2 = kb2 + (size_t)BB * SS * DD;

    dim3 gw(16, 16, 7);   // z=0..3 wT; z=4..6 q/k/v -> bf16
    wtrans_kernel<<<gw, 256, 0, stream>>>(wq, wk, wv, wo, q, k, v,
                                          wtq, wtk, wtv, wto, qb, kb2, vb2);

    dim3 gg(32, 8, 4);    // z=0: mask pack; z=1..3: q/k/v projections
    proj3_kernel<<<gg, 256, 0, stream>>>(qb, kb2, vb2, wtq, wtk, wtv, bq, bk, bv,
                                         qhp, khp, vTp, mask, bits);
    attn_compute_kernel<<<BB * HH * 16, 512, 0, stream>>>(qhp, khp, vTp, bits, linvb, ctx);

    dim3 gm(32, 8, 33);   // z=0: outproj; z=1..32: attn store slices (8192)
    outstore_kernel<<<gm, 256, 0, stream>>>(ctx, wto, bo, q, out,
                                            qhp, khp, bits, linvb, attn);
    ln_kernel<<<BB * SS, 256, 0, stream>>>(out, gamma, beta);
}